// Round 1
// baseline (288.521 us; speedup 1.0000x reference)
//
#include <hip/hip_runtime.h>

#define Bb 16
#define Cc 256
#define HW 4096
#define Nn 65536
#define Kk 512

typedef __attribute__((ext_vector_type(4))) float f32x4;
typedef __attribute__((ext_vector_type(8))) short short8;

__device__ __forceinline__ float bf2f(unsigned short u){
  union { float f; unsigned int i; } v; v.i = ((unsigned int)u) << 16; return v.f;
}
__device__ __forceinline__ unsigned short f2bf(float f){
  unsigned int i = __float_as_uint(f);
  unsigned int r = (i + 0x7fffu + ((i >> 16) & 1u)) >> 16;
  return (unsigned short)r;
}

// ---------------- K0: per-pixel L2 norm of x (b,c,h,w) ----------------
__global__ __launch_bounds__(256) void k_norms(const float* __restrict__ x,
                                               float* __restrict__ norm){
  int t = threadIdx.x, w = t >> 6, l = t & 63;
  int blk = blockIdx.x;              // 256 blocks, 256 px each
  int b = blk >> 4;
  int hw0 = (blk & 15) << 8;
  const float* xb = x + (size_t)b * Cc * HW + hw0 + l * 4;
  float a0=0.f,a1=0.f,a2=0.f,a3=0.f;
  #pragma unroll 4
  for (int cc = 0; cc < 64; ++cc){
    int c = w * 64 + cc;
    float4 v = *reinterpret_cast<const float4*>(xb + (size_t)c * HW);
    a0 += v.x*v.x; a1 += v.y*v.y; a2 += v.z*v.z; a3 += v.w*v.w;
  }
  __shared__ float red[4][256];
  red[w][l*4+0]=a0; red[w][l*4+1]=a1; red[w][l*4+2]=a2; red[w][l*4+3]=a3;
  __syncthreads();
  float ss = red[0][t] + red[1][t] + red[2][t] + red[3][t];
  norm[(size_t)b * HW + hw0 + t] = fmaxf(sqrtf(ss), 1e-12f);
}

// ---------------- K1: transpose (b,c,hw)->(px,c), normalize, bf16 ----------------
__global__ __launch_bounds__(256) void k_transpose(const float* __restrict__ x,
                                                   const float* __restrict__ norm,
                                                   unsigned short* __restrict__ xn){
  __shared__ float tile[64][65];
  int t = threadIdx.x;
  int blk = blockIdx.x;              // 4096 blocks
  int b  = blk >> 8;
  int tl = blk & 255;
  int c0  = (tl >> 6) * 64;
  int hw0 = (tl & 63) * 64;
  int r = t >> 2, q = t & 3;
  const float* src = x + ((size_t)b * Cc + c0 + r) * HW + hw0 + q * 16;
  float4 v0 = reinterpret_cast<const float4*>(src)[0];
  float4 v1 = reinterpret_cast<const float4*>(src)[1];
  float4 v2 = reinterpret_cast<const float4*>(src)[2];
  float4 v3 = reinterpret_cast<const float4*>(src)[3];
  int cb = q * 16;
  tile[r][cb+ 0]=v0.x; tile[r][cb+ 1]=v0.y; tile[r][cb+ 2]=v0.z; tile[r][cb+ 3]=v0.w;
  tile[r][cb+ 4]=v1.x; tile[r][cb+ 5]=v1.y; tile[r][cb+ 6]=v1.z; tile[r][cb+ 7]=v1.w;
  tile[r][cb+ 8]=v2.x; tile[r][cb+ 9]=v2.y; tile[r][cb+10]=v2.z; tile[r][cb+11]=v2.w;
  tile[r][cb+12]=v3.x; tile[r][cb+13]=v3.y; tile[r][cb+14]=v3.z; tile[r][cb+15]=v3.w;
  __syncthreads();
  int wv = t >> 6, c = t & 63;
  #pragma unroll
  for (int j = 0; j < 16; ++j){
    int p = j * 4 + wv;
    float rs = 1.0f / norm[(size_t)b * HW + hw0 + p];
    xn[((size_t)b * HW + hw0 + p) * Cc + c0 + c] = f2bf(tile[c][p] * rs);
  }
}

// ---------------- K1b: normalize codebook m -> mn bf16 ----------------
__global__ __launch_bounds__(64) void k_mnorm(const float* __restrict__ m,
                                              unsigned short* __restrict__ mn){
  int k = blockIdx.x, l = threadIdx.x;
  float4 v = *reinterpret_cast<const float4*>(m + (size_t)k * Cc + l * 4);
  float ss = v.x*v.x + v.y*v.y + v.z*v.z + v.w*v.w;
  #pragma unroll
  for (int off = 1; off < 64; off <<= 1) ss += __shfl_xor(ss, off, 64);
  float rn = 1.0f / fmaxf(sqrtf(ss), 1e-12f);
  ushort4 o;
  o.x = f2bf(v.x*rn); o.y = f2bf(v.y*rn); o.z = f2bf(v.z*rn); o.w = f2bf(v.w*rn);
  *reinterpret_cast<ushort4*>(mn + (size_t)k * Cc + l * 4) = o;
}

// ---------------- K2: score = xn @ mn^T, per-pixel argmax ----------------
__global__ __launch_bounds__(256) void k_score_argmax(const unsigned short* __restrict__ xn,
                                                      const unsigned short* __restrict__ mn,
                                                      int* __restrict__ eind){
  __shared__ __align__(16) char smem[32768];   // xn tile [64][512B], XOR-swizzled
  __shared__ float smax[4][64];
  __shared__ int   sidx[4][64];
  int t = threadIdx.x, w = t >> 6, l = t & 63, gr = l >> 4, li = l & 15;
  int px0 = blockIdx.x * 64;
  const char* gsrc = reinterpret_cast<const char*>(xn + (size_t)px0 * Cc);
  #pragma unroll
  for (int j = 0; j < 8; ++j){
    int chunk = j * 256 + t;
    int rr = chunk >> 5, slot = chunk & 31;
    int4 v = *reinterpret_cast<const int4*>(gsrc + rr * 512 + slot * 16);
    *reinterpret_cast<int4*>(smem + rr * 512 + ((slot * 16) ^ ((rr & 7) << 4))) = v;
  }
  __syncthreads();
  f32x4 acc[4][8];
  #pragma unroll
  for (int mt = 0; mt < 4; ++mt)
    #pragma unroll
    for (int nt = 0; nt < 8; ++nt)
      acc[mt][nt] = (f32x4){0.f,0.f,0.f,0.f};
  const short* mnp = reinterpret_cast<const short*>(mn);
  for (int ks = 0; ks < 8; ++ks){
    short8 af[4];
    #pragma unroll
    for (int mt = 0; mt < 4; ++mt){
      int row = mt * 16 + li;
      af[mt] = *reinterpret_cast<const short8*>(
          smem + row * 512 + ((ks * 64 + gr * 16) ^ ((row & 7) << 4)));
    }
    #pragma unroll
    for (int nt = 0; nt < 8; ++nt){
      short8 bv = *reinterpret_cast<const short8*>(
          mnp + (size_t)(w * 128 + nt * 16 + li) * Cc + ks * 32 + gr * 8);
      #pragma unroll
      for (int mt = 0; mt < 4; ++mt)
        acc[mt][nt] = __builtin_amdgcn_mfma_f32_16x16x32_bf16(af[mt], bv, acc[mt][nt], 0, 0, 0);
    }
  }
  #pragma unroll
  for (int mt = 0; mt < 4; ++mt){
    #pragma unroll
    for (int r = 0; r < 4; ++r){
      float best = acc[mt][0][r]; int bi = w * 128 + li;
      #pragma unroll
      for (int nt = 1; nt < 8; ++nt){
        float v = acc[mt][nt][r]; int ii = w * 128 + nt * 16 + li;
        if (v > best){ best = v; bi = ii; }
      }
      #pragma unroll
      for (int off = 1; off < 16; off <<= 1){
        float ov = __shfl_xor(best, off, 64);
        int   oi = __shfl_xor(bi,   off, 64);
        if (ov > best || (ov == best && oi < bi)){ best = ov; bi = oi; }
      }
      if (li == 0){ int pr = mt * 16 + gr * 4 + r; smax[w][pr] = best; sidx[w][pr] = bi; }
    }
  }
  __syncthreads();
  if (t < 64){
    float best = smax[0][t]; int bi = sidx[0][t];
    #pragma unroll
    for (int ww = 1; ww < 4; ++ww){
      float v = smax[ww][t]; int ii = sidx[ww][t];
      if (v > best || (v == best && ii < bi)){ best = v; bi = ii; }
    }
    eind[px0 + t] = bi;
  }
}

// ---------------- K3: deterministic segment-sum (one block per k) ----------------
__global__ __launch_bounds__(256) void k_segsum(const int* __restrict__ eind,
                                                const unsigned short* __restrict__ xn,
                                                const float* __restrict__ norm,
                                                float* __restrict__ esum,
                                                float* __restrict__ ecnt){
  int k = blockIdx.x, t = threadIdx.x, w = t >> 6, l = t & 63;
  float a0=0.f,a1=0.f,a2=0.f,a3=0.f;
  int cnt = 0;
  int base = w * 16384;
  for (int it = 0; it < 256; ++it){
    int pxb = base + it * 64;
    int id = eind[pxb + l];
    unsigned long long mask = __ballot(id == k);
    cnt += (int)__popcll(mask);
    while (mask){
      int src = __ffsll((unsigned long long)mask) - 1;
      mask &= mask - 1;
      int mpx = pxb + src;
      float nn = norm[mpx];
      ushort4 uv = *reinterpret_cast<const ushort4*>(xn + (size_t)mpx * Cc + l * 4);
      a0 += bf2f(uv.x) * nn; a1 += bf2f(uv.y) * nn;
      a2 += bf2f(uv.z) * nn; a3 += bf2f(uv.w) * nn;
    }
  }
  __shared__ float red[4][256];
  __shared__ float rcnt[4];
  red[w][l*4+0]=a0; red[w][l*4+1]=a1; red[w][l*4+2]=a2; red[w][l*4+3]=a3;
  if (l == 0) rcnt[w] = (float)cnt;
  __syncthreads();
  float s = red[0][t] + red[1][t] + red[2][t] + red[3][t];
  esum[(size_t)k * Cc + t] = s;
  if (t == 0) ecnt[k] = rcnt[0] + rcnt[1] + rcnt[2] + rcnt[3];
}

// ---------------- K4: EMA update -> mn2 (normalized bf16) + new_m^T (raw bf16) ----------------
__global__ __launch_bounds__(64) void k_update(const float* __restrict__ esum,
                                               const float* __restrict__ ecnt,
                                               const float* __restrict__ m,
                                               unsigned short* __restrict__ mn2,
                                               unsigned short* __restrict__ nmT){
  int k = blockIdx.x, l = threadIdx.x;
  float4 s  = *reinterpret_cast<const float4*>(esum + (size_t)k * Cc + l * 4);
  float4 mv = *reinterpret_cast<const float4*>(m    + (size_t)k * Cc + l * 4);
  float inv = 1.0f / (ecnt[k] + 1e-6f);
  float nx = mv.x * 0.999f + s.x * inv * 0.001f;
  float ny = mv.y * 0.999f + s.y * inv * 0.001f;
  float nz = mv.z * 0.999f + s.z * inv * 0.001f;
  float nw = mv.w * 0.999f + s.w * inv * 0.001f;
  float ss = nx*nx + ny*ny + nz*nz + nw*nw;
  #pragma unroll
  for (int off = 1; off < 64; off <<= 1) ss += __shfl_xor(ss, off, 64);
  float rn = 1.0f / fmaxf(sqrtf(ss), 1e-12f);
  ushort4 o;
  o.x = f2bf(nx*rn); o.y = f2bf(ny*rn); o.z = f2bf(nz*rn); o.w = f2bf(nw*rn);
  *reinterpret_cast<ushort4*>(mn2 + (size_t)k * Cc + l * 4) = o;
  nmT[(size_t)(l*4+0) * Kk + k] = f2bf(nx);
  nmT[(size_t)(l*4+1) * Kk + k] = f2bf(ny);
  nmT[(size_t)(l*4+2) * Kk + k] = f2bf(nz);
  nmT[(size_t)(l*4+3) * Kk + k] = f2bf(nw);
}

// ---------------- K5: score2 -> softmax -> out (fused) ----------------
__global__ __launch_bounds__(256) void k_out(const unsigned short* __restrict__ xn,
                                             const unsigned short* __restrict__ mn2,
                                             const unsigned short* __restrict__ nmT,
                                             float* __restrict__ out,
                                             float* __restrict__ score2){
  __shared__ __align__(16) char smem[65536];   // xn tile (32K) -> P tile (64K) -> out tile (34K)
  __shared__ float wbuf[4 * 64];
  __shared__ float gmax[64];
  __shared__ float rz[64];
  int t = threadIdx.x, w = t >> 6, l = t & 63, gr = l >> 4, li = l & 15;
  int px0 = blockIdx.x * 64;
  // stage xn tile, swizzled
  const char* gsrc = reinterpret_cast<const char*>(xn + (size_t)px0 * Cc);
  #pragma unroll
  for (int j = 0; j < 8; ++j){
    int chunk = j * 256 + t;
    int rr = chunk >> 5, slot = chunk & 31;
    int4 v = *reinterpret_cast<const int4*>(gsrc + rr * 512 + slot * 16);
    *reinterpret_cast<int4*>(smem + rr * 512 + ((slot * 16) ^ ((rr & 7) << 4))) = v;
  }
  __syncthreads();
  // GEMM1: score2 tile = xn @ mn2^T   (64px x 512k, wave w owns k in [w*128, w*128+128))
  f32x4 acc[4][8];
  #pragma unroll
  for (int mt = 0; mt < 4; ++mt)
    #pragma unroll
    for (int nt = 0; nt < 8; ++nt)
      acc[mt][nt] = (f32x4){0.f,0.f,0.f,0.f};
  const short* mnp = reinterpret_cast<const short*>(mn2);
  for (int ks = 0; ks < 8; ++ks){
    short8 af[4];
    #pragma unroll
    for (int mt = 0; mt < 4; ++mt){
      int row = mt * 16 + li;
      af[mt] = *reinterpret_cast<const short8*>(
          smem + row * 512 + ((ks * 64 + gr * 16) ^ ((row & 7) << 4)));
    }
    #pragma unroll
    for (int nt = 0; nt < 8; ++nt){
      short8 bv = *reinterpret_cast<const short8*>(
          mnp + (size_t)(w * 128 + nt * 16 + li) * Cc + ks * 32 + gr * 8);
      #pragma unroll
      for (int mt = 0; mt < 4; ++mt)
        acc[mt][nt] = __builtin_amdgcn_mfma_f32_16x16x32_bf16(af[mt], bv, acc[mt][nt], 0, 0, 0);
    }
  }
  // store raw score2 + per-pixel max
  float* s2 = score2 + (size_t)px0 * Kk;
  #pragma unroll
  for (int mt = 0; mt < 4; ++mt){
    #pragma unroll
    for (int r = 0; r < 4; ++r){
      int pr = mt * 16 + gr * 4 + r;
      float mx = -3.4e38f;
      #pragma unroll
      for (int nt = 0; nt < 8; ++nt){
        float v = acc[mt][nt][r];
        s2[(size_t)pr * Kk + w * 128 + nt * 16 + li] = v;
        mx = fmaxf(mx, v);
      }
      #pragma unroll
      for (int off = 1; off < 16; off <<= 1) mx = fmaxf(mx, __shfl_xor(mx, off, 64));
      if (li == 0) wbuf[w * 64 + pr] = mx;
    }
  }
  __syncthreads();
  if (t < 64)
    gmax[t] = fmaxf(fmaxf(wbuf[t], wbuf[64 + t]), fmaxf(wbuf[128 + t], wbuf[192 + t]));
  __syncthreads();
  // exp, write P (bf16, swizzled, overlays dead xn tile), per-pixel sum
  #pragma unroll
  for (int mt = 0; mt < 4; ++mt){
    #pragma unroll
    for (int r = 0; r < 4; ++r){
      int pr = mt * 16 + gr * 4 + r;
      float g = gmax[pr];
      float s = 0.f;
      #pragma unroll
      for (int nt = 0; nt < 8; ++nt){
        float p = __expf(acc[mt][nt][r] - g);
        s += p;
        int colb = (w * 128 + nt * 16 + li) * 2;
        *reinterpret_cast<unsigned short*>(smem + pr * 1024 + (colb ^ ((pr & 7) << 4))) = f2bf(p);
      }
      #pragma unroll
      for (int off = 1; off < 16; off <<= 1) s += __shfl_xor(s, off, 64);
      if (li == 0) wbuf[w * 64 + pr] = s;
    }
  }
  __syncthreads();
  if (t < 64) rz[t] = 1.0f / (wbuf[t] + wbuf[64 + t] + wbuf[128 + t] + wbuf[192 + t]);
  // GEMM2: out tile = P @ new_m   (wave w owns c in [w*64, w*64+64))
  f32x4 acc2[4][4];
  #pragma unroll
  for (int mt = 0; mt < 4; ++mt)
    #pragma unroll
    for (int nt = 0; nt < 4; ++nt)
      acc2[mt][nt] = (f32x4){0.f,0.f,0.f,0.f};
  const short* nmp = reinterpret_cast<const short*>(nmT);
  int c0w = w * 64;
  for (int ks = 0; ks < 16; ++ks){
    short8 af[4];
    #pragma unroll
    for (int mt = 0; mt < 4; ++mt){
      int row = mt * 16 + li;
      af[mt] = *reinterpret_cast<const short8*>(
          smem + row * 1024 + ((ks * 64 + gr * 16) ^ ((row & 7) << 4)));
    }
    #pragma unroll
    for (int nt = 0; nt < 4; ++nt){
      short8 bv = *reinterpret_cast<const short8*>(
          nmp + (size_t)(c0w + nt * 16 + li) * Kk + ks * 32 + gr * 8);
      #pragma unroll
      for (int mt = 0; mt < 4; ++mt)
        acc2[mt][nt] = __builtin_amdgcn_mfma_f32_16x16x32_bf16(af[mt], bv, acc2[mt][nt], 0, 0, 0);
    }
  }
  __syncthreads();   // P dead; rz visible
  // epilogue: transpose via LDS so (b,c,h,w) writes are 256B-contiguous
  float* ldsO = reinterpret_cast<float*>(smem);     // [128][67]
  int b = px0 >> 12, hw0 = px0 & 4095;
  if (w < 2){
    #pragma unroll
    for (int mt = 0; mt < 4; ++mt)
      #pragma unroll
      for (int nt = 0; nt < 4; ++nt)
        #pragma unroll
        for (int r = 0; r < 4; ++r){
          int cl = w * 64 + nt * 16 + li;
          int pr = mt * 16 + gr * 4 + r;
          ldsO[cl * 67 + pr] = acc2[mt][nt][r] * rz[pr];
        }
  }
  __syncthreads();
  #pragma unroll
  for (int j = 0; j < 32; ++j){
    int cl = j * 4 + w;
    out[((size_t)b * Cc + cl) * HW + hw0 + l] = ldsO[cl * 67 + l];
  }
  __syncthreads();
  if (w >= 2){
    #pragma unroll
    for (int mt = 0; mt < 4; ++mt)
      #pragma unroll
      for (int nt = 0; nt < 4; ++nt)
        #pragma unroll
        for (int r = 0; r < 4; ++r){
          int cl = (w - 2) * 64 + nt * 16 + li;
          int pr = mt * 16 + gr * 4 + r;
          ldsO[cl * 67 + pr] = acc2[mt][nt][r] * rz[pr];
        }
  }
  __syncthreads();
  #pragma unroll
  for (int j = 0; j < 32; ++j){
    int cl = j * 4 + w;
    out[((size_t)b * Cc + 128 + cl) * HW + hw0 + l] = ldsO[cl * 67 + l];
  }
}

extern "C" void kernel_launch(void* const* d_in, const int* in_sizes, int n_in,
                              void* d_out, int out_size, void* d_ws, size_t ws_size,
                              hipStream_t stream) {
  (void)in_sizes; (void)n_in; (void)out_size; (void)ws_size;
  const float* x = (const float*)d_in[0];   // (16,256,64,64)
  const float* m = (const float*)d_in[1];   // (512,256)
  float* out    = (float*)d_out;                       // 16777216 f32
  float* score2 = (float*)d_out + (size_t)Nn * Cc;     // 33554432 f32

  char* ws = (char*)d_ws;
  unsigned short* xn  = (unsigned short*)(ws);                 // 33554432 B
  float*          nrm = (float*)(ws + 33554432);               //   262144 B
  unsigned short* mn  = (unsigned short*)(ws + 33816576);      //   262144 B
  int*            ei  = (int*)(ws + 34078720);                 //   262144 B
  float*          es  = (float*)(ws + 34340864);               //   524288 B
  float*          ec  = (float*)(ws + 34865152);               //     2048 B
  unsigned short* mn2 = (unsigned short*)(ws + 34867200);      //   262144 B
  unsigned short* nmT = (unsigned short*)(ws + 35129344);      //   262144 B
  // total ws use: ~35.4 MB

  k_norms       <<<256,  256, 0, stream>>>(x, nrm);
  k_transpose   <<<4096, 256, 0, stream>>>(x, nrm, xn);
  k_mnorm       <<<512,  64,  0, stream>>>(m, mn);
  k_score_argmax<<<1024, 256, 0, stream>>>(xn, mn, ei);
  k_segsum      <<<512,  256, 0, stream>>>(ei, xn, nrm, es, ec);
  k_update      <<<512,  64,  0, stream>>>(es, ec, m, mn2, nmT);
  k_out         <<<1024, 256, 0, stream>>>(xn, mn2, nmT, out, score2);
}

// Round 2
// 239.155 us; speedup vs baseline: 1.2064x; 1.2064x over previous
//
#include <hip/hip_runtime.h>

#define Bb 16
#define Cc 256
#define HW 4096
#define Nn 65536
#define Kk 512

typedef __attribute__((ext_vector_type(4))) float f32x4;
typedef __attribute__((ext_vector_type(8))) short short8;

__device__ __forceinline__ float bf2f(unsigned short u){
  union { float f; unsigned int i; } v; v.i = ((unsigned int)u) << 16; return v.f;
}
__device__ __forceinline__ unsigned short f2bf(float f){
  unsigned int i = __float_as_uint(f);
  unsigned int r = (i + 0x7fffu + ((i >> 16) & 1u)) >> 16;
  return (unsigned short)r;
}

// ---------------- K0: per-pixel L2 norm of x (b,c,h,w) ----------------
// 1024 blocks (b, 64-px strip), 256 thr: lane l = pixel, wave = channel quarter.
__global__ __launch_bounds__(256) void k_norms(const float* __restrict__ x,
                                               float* __restrict__ norm){
  int t = threadIdx.x, cq = t >> 6, l = t & 63;
  int blk = blockIdx.x;
  int b = blk >> 6;
  int hw0 = (blk & 63) << 6;
  const float* xb = x + ((size_t)b * Cc + cq * 64) * HW + hw0 + l;
  float ss = 0.f;
  #pragma unroll 8
  for (int j = 0; j < 64; ++j)
    { float v = xb[(size_t)j * HW]; ss += v * v; }
  __shared__ float red[4][64];
  red[cq][l] = ss;
  __syncthreads();
  if (t < 64){
    float s = red[0][t] + red[1][t] + red[2][t] + red[3][t];
    norm[(size_t)b * HW + hw0 + t] = fmaxf(sqrtf(s), 1e-12f);
  }
}

// ---------------- K1: transpose (b,c,hw)->(px,c), normalize, bf16 ----------------
__global__ __launch_bounds__(256) void k_transpose(const float* __restrict__ x,
                                                   const float* __restrict__ norm,
                                                   unsigned short* __restrict__ xn){
  __shared__ float tile[64][65];
  int t = threadIdx.x;
  int blk = blockIdx.x;              // 4096 blocks
  int b  = blk >> 8;
  int tl = blk & 255;
  int c0  = (tl >> 6) * 64;
  int hw0 = (tl & 63) * 64;
  int r = t >> 2, q = t & 3;
  const float* src = x + ((size_t)b * Cc + c0 + r) * HW + hw0 + q * 16;
  float4 v0 = reinterpret_cast<const float4*>(src)[0];
  float4 v1 = reinterpret_cast<const float4*>(src)[1];
  float4 v2 = reinterpret_cast<const float4*>(src)[2];
  float4 v3 = reinterpret_cast<const float4*>(src)[3];
  int cb = q * 16;
  tile[r][cb+ 0]=v0.x; tile[r][cb+ 1]=v0.y; tile[r][cb+ 2]=v0.z; tile[r][cb+ 3]=v0.w;
  tile[r][cb+ 4]=v1.x; tile[r][cb+ 5]=v1.y; tile[r][cb+ 6]=v1.z; tile[r][cb+ 7]=v1.w;
  tile[r][cb+ 8]=v2.x; tile[r][cb+ 9]=v2.y; tile[r][cb+10]=v2.z; tile[r][cb+11]=v2.w;
  tile[r][cb+12]=v3.x; tile[r][cb+13]=v3.y; tile[r][cb+14]=v3.z; tile[r][cb+15]=v3.w;
  __syncthreads();
  int wv = t >> 6, c = t & 63;
  #pragma unroll
  for (int j = 0; j < 16; ++j){
    int p = j * 4 + wv;
    float rs = 1.0f / norm[(size_t)b * HW + hw0 + p];
    xn[((size_t)b * HW + hw0 + p) * Cc + c0 + c] = f2bf(tile[c][p] * rs);
  }
}

// ---------------- K1b: normalize codebook m -> mn bf16 ----------------
__global__ __launch_bounds__(64) void k_mnorm(const float* __restrict__ m,
                                              unsigned short* __restrict__ mn){
  int k = blockIdx.x, l = threadIdx.x;
  float4 v = *reinterpret_cast<const float4*>(m + (size_t)k * Cc + l * 4);
  float ss = v.x*v.x + v.y*v.y + v.z*v.z + v.w*v.w;
  #pragma unroll
  for (int off = 1; off < 64; off <<= 1) ss += __shfl_xor(ss, off, 64);
  float rn = 1.0f / fmaxf(sqrtf(ss), 1e-12f);
  ushort4 o;
  o.x = f2bf(v.x*rn); o.y = f2bf(v.y*rn); o.z = f2bf(v.z*rn); o.w = f2bf(v.w*rn);
  *reinterpret_cast<ushort4*>(mn + (size_t)k * Cc + l * 4) = o;
}

// ---------------- K2: score = xn @ mn^T, per-pixel argmax (512 thr, 8 waves) ----------------
__global__ __launch_bounds__(512, 4) void k_score_argmax(const unsigned short* __restrict__ xn,
                                                         const unsigned short* __restrict__ mn,
                                                         int* __restrict__ eind){
  __shared__ __align__(16) char smem[32768];   // xn tile [64][512B], XOR-swizzled
  __shared__ float smax[8][64];
  __shared__ int   sidx[8][64];
  int t = threadIdx.x, w = t >> 6, l = t & 63, gr = l >> 4, li = l & 15;
  int px0 = blockIdx.x * 64;
  const char* gsrc = reinterpret_cast<const char*>(xn + (size_t)px0 * Cc);
  #pragma unroll
  for (int j = 0; j < 4; ++j){
    int chunk = j * 512 + t;
    int rr = chunk >> 5, slot = chunk & 31;
    int4 v = *reinterpret_cast<const int4*>(gsrc + rr * 512 + slot * 16);
    *reinterpret_cast<int4*>(smem + rr * 512 + ((slot * 16) ^ ((rr & 7) << 4))) = v;
  }
  __syncthreads();
  f32x4 acc[4][4];
  #pragma unroll
  for (int mt = 0; mt < 4; ++mt)
    #pragma unroll
    for (int nt = 0; nt < 4; ++nt)
      acc[mt][nt] = (f32x4){0.f,0.f,0.f,0.f};
  const short* mnp = reinterpret_cast<const short*>(mn);
  for (int ks = 0; ks < 8; ++ks){
    short8 af[4];
    #pragma unroll
    for (int mt = 0; mt < 4; ++mt){
      int row = mt * 16 + li;
      af[mt] = *reinterpret_cast<const short8*>(
          smem + row * 512 + ((ks * 64 + gr * 16) ^ ((row & 7) << 4)));
    }
    #pragma unroll
    for (int nt = 0; nt < 4; ++nt){
      short8 bv = *reinterpret_cast<const short8*>(
          mnp + (size_t)(w * 64 + nt * 16 + li) * Cc + ks * 32 + gr * 8);
      #pragma unroll
      for (int mt = 0; mt < 4; ++mt)
        acc[mt][nt] = __builtin_amdgcn_mfma_f32_16x16x32_bf16(af[mt], bv, acc[mt][nt], 0, 0, 0);
    }
  }
  #pragma unroll
  for (int mt = 0; mt < 4; ++mt){
    #pragma unroll
    for (int r = 0; r < 4; ++r){
      float best = acc[mt][0][r]; int bi = w * 64 + li;
      #pragma unroll
      for (int nt = 1; nt < 4; ++nt){
        float v = acc[mt][nt][r]; int ii = w * 64 + nt * 16 + li;
        if (v > best){ best = v; bi = ii; }
      }
      #pragma unroll
      for (int off = 1; off < 16; off <<= 1){
        float ov = __shfl_xor(best, off, 64);
        int   oi = __shfl_xor(bi,   off, 64);
        if (ov > best || (ov == best && oi < bi)){ best = ov; bi = oi; }
      }
      if (li == 0){ int pr = mt * 16 + gr * 4 + r; smax[w][pr] = best; sidx[w][pr] = bi; }
    }
  }
  __syncthreads();
  if (t < 64){
    float best = smax[0][t]; int bi = sidx[0][t];
    #pragma unroll
    for (int ww = 1; ww < 8; ++ww){
      float v = smax[ww][t]; int ii = sidx[ww][t];
      if (v > best || (v == best && ii < bi)){ best = v; bi = ii; }
    }
    eind[px0 + t] = bi;
  }
}

// ---------------- K3: deterministic segment-sum (one block per k) ----------------
__global__ __launch_bounds__(256) void k_segsum(const int* __restrict__ eind,
                                                const unsigned short* __restrict__ xn,
                                                const float* __restrict__ norm,
                                                float* __restrict__ esum,
                                                float* __restrict__ ecnt){
  int k = blockIdx.x, t = threadIdx.x, w = t >> 6, l = t & 63;
  float a0=0.f,a1=0.f,a2=0.f,a3=0.f;
  int cnt = 0;
  int base = w * 16384;
  for (int it = 0; it < 256; ++it){
    int pxb = base + it * 64;
    int id = eind[pxb + l];
    unsigned long long mask = __ballot(id == k);
    cnt += (int)__popcll(mask);
    while (mask){
      int src = __ffsll((unsigned long long)mask) - 1;
      mask &= mask - 1;
      int mpx = pxb + src;
      float nn = norm[mpx];
      ushort4 uv = *reinterpret_cast<const ushort4*>(xn + (size_t)mpx * Cc + l * 4);
      a0 += bf2f(uv.x) * nn; a1 += bf2f(uv.y) * nn;
      a2 += bf2f(uv.z) * nn; a3 += bf2f(uv.w) * nn;
    }
  }
  __shared__ float red[4][256];
  __shared__ float rcnt[4];
  red[w][l*4+0]=a0; red[w][l*4+1]=a1; red[w][l*4+2]=a2; red[w][l*4+3]=a3;
  if (l == 0) rcnt[w] = (float)cnt;
  __syncthreads();
  float s = red[0][t] + red[1][t] + red[2][t] + red[3][t];
  esum[(size_t)k * Cc + t] = s;
  if (t == 0) ecnt[k] = rcnt[0] + rcnt[1] + rcnt[2] + rcnt[3];
}

// ---------------- K4: EMA update -> mn2 (normalized bf16) + new_m^T (raw bf16) ----------------
__global__ __launch_bounds__(64) void k_update(const float* __restrict__ esum,
                                               const float* __restrict__ ecnt,
                                               const float* __restrict__ m,
                                               unsigned short* __restrict__ mn2,
                                               unsigned short* __restrict__ nmT){
  int k = blockIdx.x, l = threadIdx.x;
  float4 s  = *reinterpret_cast<const float4*>(esum + (size_t)k * Cc + l * 4);
  float4 mv = *reinterpret_cast<const float4*>(m    + (size_t)k * Cc + l * 4);
  float inv = 1.0f / (ecnt[k] + 1e-6f);
  float nx = mv.x * 0.999f + s.x * inv * 0.001f;
  float ny = mv.y * 0.999f + s.y * inv * 0.001f;
  float nz = mv.z * 0.999f + s.z * inv * 0.001f;
  float nw = mv.w * 0.999f + s.w * inv * 0.001f;
  float ss = nx*nx + ny*ny + nz*nz + nw*nw;
  #pragma unroll
  for (int off = 1; off < 64; off <<= 1) ss += __shfl_xor(ss, off, 64);
  float rn = 1.0f / fmaxf(sqrtf(ss), 1e-12f);
  ushort4 o;
  o.x = f2bf(nx*rn); o.y = f2bf(ny*rn); o.z = f2bf(nz*rn); o.w = f2bf(nw*rn);
  *reinterpret_cast<ushort4*>(mn2 + (size_t)k * Cc + l * 4) = o;
  nmT[(size_t)(l*4+0) * Kk + k] = f2bf(nx);
  nmT[(size_t)(l*4+1) * Kk + k] = f2bf(ny);
  nmT[(size_t)(l*4+2) * Kk + k] = f2bf(nz);
  nmT[(size_t)(l*4+3) * Kk + k] = f2bf(nw);
}

// ---------------- K5: score2 -> softmax -> out (fused, 512 thr / 8 waves) ----------------
__global__ __launch_bounds__(512, 4) void k_out(const unsigned short* __restrict__ xn,
                                                const unsigned short* __restrict__ mn2,
                                                const unsigned short* __restrict__ nmT,
                                                float* __restrict__ out,
                                                float* __restrict__ score2){
  __shared__ __align__(16) char smem[65536];   // xn tile (32K, overlaid) -> P tile (64K)
  __shared__ float wbuf[8 * 64];
  __shared__ float gmax[64];
  __shared__ float rz[64];
  int t = threadIdx.x, w = t >> 6, l = t & 63, gr = l >> 4, li = l & 15;
  int px0 = blockIdx.x * 64;
  // stage xn tile, swizzled (rows 64 x 512B)
  const char* gsrc = reinterpret_cast<const char*>(xn + (size_t)px0 * Cc);
  #pragma unroll
  for (int j = 0; j < 4; ++j){
    int chunk = j * 512 + t;
    int rr = chunk >> 5, slot = chunk & 31;
    int4 v = *reinterpret_cast<const int4*>(gsrc + rr * 512 + slot * 16);
    *reinterpret_cast<int4*>(smem + rr * 512 + ((slot * 16) ^ ((rr & 7) << 4))) = v;
  }
  __syncthreads();
  // GEMM1: score2 tile = xn @ mn2^T  (wave w owns k in [w*64, w*64+64))
  f32x4 acc[4][4];
  #pragma unroll
  for (int mt = 0; mt < 4; ++mt)
    #pragma unroll
    for (int nt = 0; nt < 4; ++nt)
      acc[mt][nt] = (f32x4){0.f,0.f,0.f,0.f};
  const short* mnp = reinterpret_cast<const short*>(mn2);
  for (int ks = 0; ks < 8; ++ks){
    short8 af[4];
    #pragma unroll
    for (int mt = 0; mt < 4; ++mt){
      int row = mt * 16 + li;
      af[mt] = *reinterpret_cast<const short8*>(
          smem + row * 512 + ((ks * 64 + gr * 16) ^ ((row & 7) << 4)));
    }
    #pragma unroll
    for (int nt = 0; nt < 4; ++nt){
      short8 bv = *reinterpret_cast<const short8*>(
          mnp + (size_t)(w * 64 + nt * 16 + li) * Cc + ks * 32 + gr * 8);
      #pragma unroll
      for (int mt = 0; mt < 4; ++mt)
        acc[mt][nt] = __builtin_amdgcn_mfma_f32_16x16x32_bf16(af[mt], bv, acc[mt][nt], 0, 0, 0);
    }
  }
  // store raw score2 + per-wave per-pixel max
  float* s2 = score2 + (size_t)px0 * Kk;
  #pragma unroll
  for (int mt = 0; mt < 4; ++mt){
    #pragma unroll
    for (int r = 0; r < 4; ++r){
      int pr = mt * 16 + gr * 4 + r;
      float mx = -3.4e38f;
      #pragma unroll
      for (int nt = 0; nt < 4; ++nt){
        float v = acc[mt][nt][r];
        s2[(size_t)pr * Kk + w * 64 + nt * 16 + li] = v;
        mx = fmaxf(mx, v);
      }
      #pragma unroll
      for (int off = 1; off < 16; off <<= 1) mx = fmaxf(mx, __shfl_xor(mx, off, 64));
      if (li == 0) wbuf[w * 64 + pr] = mx;
    }
  }
  __syncthreads();                               // wbuf ready; all GEMM1 LDS reads done
  if (t < 64){
    float g = wbuf[t];
    #pragma unroll
    for (int ww = 1; ww < 8; ++ww) g = fmaxf(g, wbuf[ww * 64 + t]);
    gmax[t] = g;
  }
  __syncthreads();                               // gmax visible
  // exp (in place) -> P bf16 to LDS (overlays xn tile), per-pixel partial sum
  #pragma unroll
  for (int mt = 0; mt < 4; ++mt){
    #pragma unroll
    for (int r = 0; r < 4; ++r){
      int pr = mt * 16 + gr * 4 + r;
      float g = gmax[pr];
      float s = 0.f;
      #pragma unroll
      for (int nt = 0; nt < 4; ++nt){
        float p = __expf(acc[mt][nt][r] - g);
        s += p;
        int colb = (w * 64 + nt * 16 + li) * 2;
        *reinterpret_cast<unsigned short*>(smem + pr * 1024 + (colb ^ ((pr & 7) << 4))) = f2bf(p);
      }
      #pragma unroll
      for (int off = 1; off < 16; off <<= 1) s += __shfl_xor(s, off, 64);
      if (li == 0) wbuf[w * 64 + pr] = s;
    }
  }
  __syncthreads();                               // P + wbuf(sums) ready
  if (t < 64){
    float s = wbuf[t];
    #pragma unroll
    for (int ww = 1; ww < 8; ++ww) s += wbuf[ww * 64 + t];
    rz[t] = 1.0f / s;
  }
  // GEMM2: out tile = P @ new_m  (wave w owns c in [w*32, w*32+32))
  f32x4 acc2[4][2];
  #pragma unroll
  for (int mt = 0; mt < 4; ++mt)
    #pragma unroll
    for (int nt = 0; nt < 2; ++nt)
      acc2[mt][nt] = (f32x4){0.f,0.f,0.f,0.f};
  const short* nmp = reinterpret_cast<const short*>(nmT);
  for (int ks = 0; ks < 16; ++ks){
    short8 af[4];
    #pragma unroll
    for (int mt = 0; mt < 4; ++mt){
      int row = mt * 16 + li;
      af[mt] = *reinterpret_cast<const short8*>(
          smem + row * 1024 + ((ks * 64 + gr * 16) ^ ((row & 7) << 4)));
    }
    #pragma unroll
    for (int nt = 0; nt < 2; ++nt){
      short8 bv = *reinterpret_cast<const short8*>(
          nmp + (size_t)(w * 32 + nt * 16 + li) * Kk + ks * 32 + gr * 8);
      #pragma unroll
      for (int mt = 0; mt < 4; ++mt)
        acc2[mt][nt] = __builtin_amdgcn_mfma_f32_16x16x32_bf16(af[mt], bv, acc2[mt][nt], 0, 0, 0);
    }
  }
  __syncthreads();                               // rz visible to all waves
  // epilogue: direct float4 stores — lane's 4 acc values are 4 consecutive px of one channel
  int b = px0 >> 12, hw0 = px0 & 4095;
  #pragma unroll
  for (int mt = 0; mt < 4; ++mt){
    int pb = mt * 16 + gr * 4;
    float r0 = rz[pb + 0], r1 = rz[pb + 1], r2 = rz[pb + 2], r3 = rz[pb + 3];
    #pragma unroll
    for (int nt = 0; nt < 2; ++nt){
      int c = w * 32 + nt * 16 + li;
      f32x4 v;
      v[0] = acc2[mt][nt][0] * r0;
      v[1] = acc2[mt][nt][1] * r1;
      v[2] = acc2[mt][nt][2] * r2;
      v[3] = acc2[mt][nt][3] * r3;
      *reinterpret_cast<f32x4*>(out + ((size_t)b * Cc + c) * HW + hw0 + pb) = v;
    }
  }
}

extern "C" void kernel_launch(void* const* d_in, const int* in_sizes, int n_in,
                              void* d_out, int out_size, void* d_ws, size_t ws_size,
                              hipStream_t stream) {
  (void)in_sizes; (void)n_in; (void)out_size; (void)ws_size;
  const float* x = (const float*)d_in[0];   // (16,256,64,64)
  const float* m = (const float*)d_in[1];   // (512,256)
  float* out    = (float*)d_out;                       // 16777216 f32
  float* score2 = (float*)d_out + (size_t)Nn * Cc;     // 33554432 f32

  char* ws = (char*)d_ws;
  unsigned short* xn  = (unsigned short*)(ws);                 // 33554432 B
  float*          nrm = (float*)(ws + 33554432);               //   262144 B
  unsigned short* mn  = (unsigned short*)(ws + 33816576);      //   262144 B
  int*            ei  = (int*)(ws + 34078720);                 //   262144 B
  float*          es  = (float*)(ws + 34340864);               //   524288 B
  float*          ec  = (float*)(ws + 34865152);               //     2048 B
  unsigned short* mn2 = (unsigned short*)(ws + 34867200);      //   262144 B
  unsigned short* nmT = (unsigned short*)(ws + 35129344);      //   262144 B

  k_norms       <<<1024, 256, 0, stream>>>(x, nrm);
  k_transpose   <<<4096, 256, 0, stream>>>(x, nrm, xn);
  k_mnorm       <<<512,  64,  0, stream>>>(m, mn);
  k_score_argmax<<<1024, 512, 0, stream>>>(xn, mn, ei);
  k_segsum      <<<512,  256, 0, stream>>>(ei, xn, nrm, es, ec);
  k_update      <<<512,  64,  0, stream>>>(es, ec, m, mn2, nmT);
  k_out         <<<1024, 512, 0, stream>>>(xn, mn2, nmT, out, score2);
}

// Round 3
// 189.598 us; speedup vs baseline: 1.5217x; 1.2614x over previous
//
#include <hip/hip_runtime.h>

#define Bb 16
#define Cc 256
#define HW 4096
#define Nn 65536
#define Kk 512

typedef __attribute__((ext_vector_type(4))) float f32x4;
typedef __attribute__((ext_vector_type(8))) short short8;

__device__ __forceinline__ float bf2f(unsigned int u){
  union { float f; unsigned int i; } v; v.i = u << 16; return v.f;
}
__device__ __forceinline__ unsigned short f2bf(float f){
  unsigned int i = __float_as_uint(f);
  unsigned int r = (i + 0x7fffu + ((i >> 16) & 1u)) >> 16;
  return (unsigned short)r;
}

// ---------------- K_prep: fused per-pixel norm + transpose + bf16 (one x pass) ----------------
// 1024 blocks = (b, 64-px strip). Thread t: channel-in-chunk cl=t>>2, px-window qq=t&3.
__global__ __launch_bounds__(256) void k_prep(const float* __restrict__ x,
                                              float* __restrict__ nrm,
                                              unsigned short* __restrict__ xn){
  __shared__ __align__(16) char ldsB[32768];   // [64 px][512 B] bf16 raw x, XOR-swizzled
  __shared__ float red2[4][64];
  __shared__ float rsb[64];
  int t = threadIdx.x, w = t >> 6;
  int b = blockIdx.x >> 6;
  int hw0 = (blockIdx.x & 63) << 6;
  int cl = t >> 2;            // 0..63 channel within chunk
  int qq = t & 3;             // 16-px window
  float aq[16];
  #pragma unroll
  for (int j = 0; j < 16; ++j) aq[j] = 0.f;
  #pragma unroll
  for (int ch = 0; ch < 4; ++ch){
    const float* src = x + ((size_t)b * Cc + ch * 64 + cl) * HW + hw0 + qq * 16;
    float4 v0 = reinterpret_cast<const float4*>(src)[0];
    float4 v1 = reinterpret_cast<const float4*>(src)[1];
    float4 v2 = reinterpret_cast<const float4*>(src)[2];
    float4 v3 = reinterpret_cast<const float4*>(src)[3];
    float vv[16] = {v0.x,v0.y,v0.z,v0.w, v1.x,v1.y,v1.z,v1.w,
                    v2.x,v2.y,v2.z,v2.w, v3.x,v3.y,v3.z,v3.w};
    int chb = ch * 128 + cl * 2;
    #pragma unroll
    for (int j = 0; j < 16; ++j){
      float v = vv[j];
      aq[j] += v * v;
      int px = qq * 16 + j;
      int sw = ((px ^ (px >> 4)) & 7) << 4;
      *reinterpret_cast<unsigned short*>(ldsB + px * 512 + (chb ^ sw)) = f2bf(v);
    }
  }
  // reduce sumsq over the wave's 16 channel-lanes (t bits 2..5)
  #pragma unroll
  for (int j = 0; j < 16; ++j){
    float s = aq[j];
    s += __shfl_xor(s, 4, 64);
    s += __shfl_xor(s, 8, 64);
    s += __shfl_xor(s, 16, 64);
    s += __shfl_xor(s, 32, 64);
    aq[j] = s;
  }
  int jj = (t >> 2) & 15;
  red2[w][qq * 16 + jj] = aq[jj];
  __syncthreads();
  if (t < 64){
    float ss = red2[0][t] + red2[1][t] + red2[2][t] + red2[3][t];
    float nn = fmaxf(sqrtf(ss), 1e-12f);
    nrm[(size_t)b * HW + hw0 + t] = nn;
    rsb[t] = 1.0f / nn;
  }
  __syncthreads();
  // writeout: scale by 1/norm, 1KB-contiguous stores per wave
  char* dstb = reinterpret_cast<char*>(xn) + (size_t)(b * HW + hw0) * 512;
  #pragma unroll
  for (int i = 0; i < 8; ++i){
    int px = i * 8 + (t >> 5);
    int colb = (t & 31) * 16;
    int sw = ((px ^ (px >> 4)) & 7) << 4;
    int4 rv = *reinterpret_cast<const int4*>(ldsB + px * 512 + (colb ^ sw));
    float rs = rsb[px];
    unsigned int uu[4] = {(unsigned int)rv.x, (unsigned int)rv.y,
                          (unsigned int)rv.z, (unsigned int)rv.w};
    #pragma unroll
    for (int q = 0; q < 4; ++q){
      float lo = bf2f(uu[q] & 0xffffu) * rs;
      float hi = bf2f(uu[q] >> 16) * rs;
      uu[q] = (unsigned int)f2bf(lo) | ((unsigned int)f2bf(hi) << 16);
    }
    int4 ov; ov.x = uu[0]; ov.y = uu[1]; ov.z = uu[2]; ov.w = uu[3];
    *reinterpret_cast<int4*>(dstb + i * 4096 + (t >> 5) * 512 + colb) = ov;
  }
}

// ---------------- K1b: normalize codebook m -> mn bf16 ----------------
__global__ __launch_bounds__(64) void k_mnorm(const float* __restrict__ m,
                                              unsigned short* __restrict__ mn){
  int k = blockIdx.x, l = threadIdx.x;
  float4 v = *reinterpret_cast<const float4*>(m + (size_t)k * Cc + l * 4);
  float ss = v.x*v.x + v.y*v.y + v.z*v.z + v.w*v.w;
  #pragma unroll
  for (int off = 1; off < 64; off <<= 1) ss += __shfl_xor(ss, off, 64);
  float rn = 1.0f / fmaxf(sqrtf(ss), 1e-12f);
  ushort4 o;
  o.x = f2bf(v.x*rn); o.y = f2bf(v.y*rn); o.z = f2bf(v.z*rn); o.w = f2bf(v.w*rn);
  *reinterpret_cast<ushort4*>(mn + (size_t)k * Cc + l * 4) = o;
}

// ---------------- K2: score = xn @ mn^T, per-pixel argmax (512 thr, 8 waves) ----------------
__global__ __launch_bounds__(512, 4) void k_score_argmax(const unsigned short* __restrict__ xn,
                                                         const unsigned short* __restrict__ mn,
                                                         int* __restrict__ eind){
  __shared__ __align__(16) char smem[32768];   // xn tile [64][512B], XOR-swizzled
  __shared__ float smax[8][64];
  __shared__ int   sidx[8][64];
  int t = threadIdx.x, w = t >> 6, l = t & 63, gr = l >> 4, li = l & 15;
  int px0 = blockIdx.x * 64;
  const char* gsrc = reinterpret_cast<const char*>(xn + (size_t)px0 * Cc);
  #pragma unroll
  for (int j = 0; j < 4; ++j){
    int chunk = j * 512 + t;
    int rr = chunk >> 5, slot = chunk & 31;
    int4 v = *reinterpret_cast<const int4*>(gsrc + rr * 512 + slot * 16);
    *reinterpret_cast<int4*>(smem + rr * 512 + ((slot * 16) ^ ((rr & 7) << 4))) = v;
  }
  __syncthreads();
  f32x4 acc[4][4];
  #pragma unroll
  for (int mt = 0; mt < 4; ++mt)
    #pragma unroll
    for (int nt = 0; nt < 4; ++nt)
      acc[mt][nt] = (f32x4){0.f,0.f,0.f,0.f};
  const short* mnp = reinterpret_cast<const short*>(mn);
  for (int ks = 0; ks < 8; ++ks){
    short8 af[4];
    #pragma unroll
    for (int mt = 0; mt < 4; ++mt){
      int row = mt * 16 + li;
      af[mt] = *reinterpret_cast<const short8*>(
          smem + row * 512 + ((ks * 64 + gr * 16) ^ ((row & 7) << 4)));
    }
    #pragma unroll
    for (int nt = 0; nt < 4; ++nt){
      short8 bv = *reinterpret_cast<const short8*>(
          mnp + (size_t)(w * 64 + nt * 16 + li) * Cc + ks * 32 + gr * 8);
      #pragma unroll
      for (int mt = 0; mt < 4; ++mt)
        acc[mt][nt] = __builtin_amdgcn_mfma_f32_16x16x32_bf16(af[mt], bv, acc[mt][nt], 0, 0, 0);
    }
  }
  #pragma unroll
  for (int mt = 0; mt < 4; ++mt){
    #pragma unroll
    for (int r = 0; r < 4; ++r){
      float best = acc[mt][0][r]; int bi = w * 64 + li;
      #pragma unroll
      for (int nt = 1; nt < 4; ++nt){
        float v = acc[mt][nt][r]; int ii = w * 64 + nt * 16 + li;
        if (v > best){ best = v; bi = ii; }
      }
      #pragma unroll
      for (int off = 1; off < 16; off <<= 1){
        float ov = __shfl_xor(best, off, 64);
        int   oi = __shfl_xor(bi,   off, 64);
        if (ov > best || (ov == best && oi < bi)){ best = ov; bi = oi; }
      }
      if (li == 0){ int pr = mt * 16 + gr * 4 + r; smax[w][pr] = best; sidx[w][pr] = bi; }
    }
  }
  __syncthreads();
  if (t < 64){
    float best = smax[0][t]; int bi = sidx[0][t];
    #pragma unroll
    for (int ww = 1; ww < 8; ++ww){
      float v = smax[ww][t]; int ii = sidx[ww][t];
      if (v > best || (v == best && ii < bi)){ best = v; bi = ii; }
    }
    eind[px0 + t] = bi;
  }
}

// ---------------- K3: deterministic segment-sum (block = (k, half), int4 eind loads) ----------------
__global__ __launch_bounds__(256) void k_segsum(const int* __restrict__ eind,
                                                const unsigned short* __restrict__ xn,
                                                const float* __restrict__ nrm,
                                                float* __restrict__ es2,
                                                float* __restrict__ ec2){
  int kk = blockIdx.x >> 1, h = blockIdx.x & 1;
  int t = threadIdx.x, w = t >> 6, l = t & 63;
  float a0=0.f,a1=0.f,a2=0.f,a3=0.f;
  int cnt = 0;
  int base = h * 32768 + w * 8192;
  for (int it = 0; it < 32; ++it){
    int pxb = base + it * 256;
    int4 e = *reinterpret_cast<const int4*>(eind + pxb + l * 4);
    #pragma unroll
    for (int comp = 0; comp < 4; ++comp){
      int ev = comp == 0 ? e.x : comp == 1 ? e.y : comp == 2 ? e.z : e.w;
      unsigned long long mask = __ballot(ev == kk);
      cnt += (int)__popcll(mask);
      while (mask){
        int src = __ffsll((unsigned long long)mask) - 1;
        mask &= mask - 1;
        int px = pxb + src * 4 + comp;
        float nn = nrm[px];
        ushort4 uv = *reinterpret_cast<const ushort4*>(xn + (size_t)px * Cc + l * 4);
        a0 += bf2f(uv.x) * nn; a1 += bf2f(uv.y) * nn;
        a2 += bf2f(uv.z) * nn; a3 += bf2f(uv.w) * nn;
      }
    }
  }
  __shared__ float red[4][256];
  __shared__ float rcnt[4];
  red[w][l*4+0]=a0; red[w][l*4+1]=a1; red[w][l*4+2]=a2; red[w][l*4+3]=a3;
  if (l == 0) rcnt[w] = (float)cnt;
  __syncthreads();
  float s = red[0][t] + red[1][t] + red[2][t] + red[3][t];
  es2[(size_t)blockIdx.x * Cc + t] = s;
  if (t == 0) ec2[blockIdx.x] = rcnt[0] + rcnt[1] + rcnt[2] + rcnt[3];
}

// ---------------- K4: EMA update (sums both halves) -> mn2 + new_m^T ----------------
__global__ __launch_bounds__(64) void k_update(const float* __restrict__ es2,
                                               const float* __restrict__ ec2,
                                               const float* __restrict__ m,
                                               unsigned short* __restrict__ mn2,
                                               unsigned short* __restrict__ nmT){
  int k = blockIdx.x, l = threadIdx.x;
  float4 s0 = *reinterpret_cast<const float4*>(es2 + ((size_t)2*k  ) * Cc + l * 4);
  float4 s1 = *reinterpret_cast<const float4*>(es2 + ((size_t)2*k+1) * Cc + l * 4);
  float4 mv = *reinterpret_cast<const float4*>(m   + (size_t)k * Cc + l * 4);
  float inv = 1.0f / (ec2[2*k] + ec2[2*k+1] + 1e-6f);
  float nx = mv.x * 0.999f + (s0.x + s1.x) * inv * 0.001f;
  float ny = mv.y * 0.999f + (s0.y + s1.y) * inv * 0.001f;
  float nz = mv.z * 0.999f + (s0.z + s1.z) * inv * 0.001f;
  float nw = mv.w * 0.999f + (s0.w + s1.w) * inv * 0.001f;
  float ss = nx*nx + ny*ny + nz*nz + nw*nw;
  #pragma unroll
  for (int off = 1; off < 64; off <<= 1) ss += __shfl_xor(ss, off, 64);
  float rn = 1.0f / fmaxf(sqrtf(ss), 1e-12f);
  ushort4 o;
  o.x = f2bf(nx*rn); o.y = f2bf(ny*rn); o.z = f2bf(nz*rn); o.w = f2bf(nw*rn);
  *reinterpret_cast<ushort4*>(mn2 + (size_t)k * Cc + l * 4) = o;
  nmT[(size_t)(l*4+0) * Kk + k] = f2bf(nx);
  nmT[(size_t)(l*4+1) * Kk + k] = f2bf(ny);
  nmT[(size_t)(l*4+2) * Kk + k] = f2bf(nz);
  nmT[(size_t)(l*4+3) * Kk + k] = f2bf(nw);
}

// ---------------- K5: score2 -> softmax (no max-shift; |s|<=1) -> out ----------------
__global__ __launch_bounds__(512, 4) void k_out(const unsigned short* __restrict__ xn,
                                                const unsigned short* __restrict__ mn2,
                                                const unsigned short* __restrict__ nmT,
                                                float* __restrict__ out,
                                                float* __restrict__ score2){
  __shared__ __align__(16) char smem[65536];   // xn tile (32K, overlaid) -> P tile (64K)
  __shared__ float wbuf[8 * 64];
  __shared__ float rz[64];
  int t = threadIdx.x, w = t >> 6, l = t & 63, gr = l >> 4, li = l & 15;
  int px0 = blockIdx.x * 64;
  const char* gsrc = reinterpret_cast<const char*>(xn + (size_t)px0 * Cc);
  #pragma unroll
  for (int j = 0; j < 4; ++j){
    int chunk = j * 512 + t;
    int rr = chunk >> 5, slot = chunk & 31;
    int4 v = *reinterpret_cast<const int4*>(gsrc + rr * 512 + slot * 16);
    *reinterpret_cast<int4*>(smem + rr * 512 + ((slot * 16) ^ ((rr & 7) << 4))) = v;
  }
  __syncthreads();
  // GEMM1: score2 tile = xn @ mn2^T  (wave w owns k in [w*64, w*64+64))
  f32x4 acc[4][4];
  #pragma unroll
  for (int mt = 0; mt < 4; ++mt)
    #pragma unroll
    for (int nt = 0; nt < 4; ++nt)
      acc[mt][nt] = (f32x4){0.f,0.f,0.f,0.f};
  const short* mnp = reinterpret_cast<const short*>(mn2);
  for (int ks = 0; ks < 8; ++ks){
    short8 af[4];
    #pragma unroll
    for (int mt = 0; mt < 4; ++mt){
      int row = mt * 16 + li;
      af[mt] = *reinterpret_cast<const short8*>(
          smem + row * 512 + ((ks * 64 + gr * 16) ^ ((row & 7) << 4)));
    }
    #pragma unroll
    for (int nt = 0; nt < 4; ++nt){
      short8 bv = *reinterpret_cast<const short8*>(
          mnp + (size_t)(w * 64 + nt * 16 + li) * Cc + ks * 32 + gr * 8);
      #pragma unroll
      for (int mt = 0; mt < 4; ++mt)
        acc[mt][nt] = __builtin_amdgcn_mfma_f32_16x16x32_bf16(af[mt], bv, acc[mt][nt], 0, 0, 0);
    }
  }
  // store raw score2; exp in place (|s|<=1.01 -> no overflow; softmax shift-invariant);
  // write P bf16 to LDS (overlays dead xn tile); per-pixel partial sums
  float* s2 = score2 + (size_t)px0 * Kk;
  __syncthreads();                               // all GEMM1 LDS reads done before P overlay
  #pragma unroll
  for (int mt = 0; mt < 4; ++mt){
    #pragma unroll
    for (int r = 0; r < 4; ++r){
      int pr = mt * 16 + gr * 4 + r;
      float s = 0.f;
      #pragma unroll
      for (int nt = 0; nt < 4; ++nt){
        float v = acc[mt][nt][r];
        s2[(size_t)pr * Kk + w * 64 + nt * 16 + li] = v;
        float p = __expf(v);
        s += p;
        int colb = (w * 64 + nt * 16 + li) * 2;
        *reinterpret_cast<unsigned short*>(smem + pr * 1024 + (colb ^ ((pr & 7) << 4))) = f2bf(p);
      }
      #pragma unroll
      for (int off = 1; off < 16; off <<= 1) s += __shfl_xor(s, off, 64);
      if (li == 0) wbuf[w * 64 + pr] = s;
    }
  }
  __syncthreads();                               // P + wbuf(sums) ready
  if (t < 64){
    float s = wbuf[t];
    #pragma unroll
    for (int ww = 1; ww < 8; ++ww) s += wbuf[ww * 64 + t];
    rz[t] = 1.0f / s;
  }
  // GEMM2: out tile = P @ new_m  (wave w owns c in [w*32, w*32+32))
  f32x4 acc2[4][2];
  #pragma unroll
  for (int mt = 0; mt < 4; ++mt)
    #pragma unroll
    for (int nt = 0; nt < 2; ++nt)
      acc2[mt][nt] = (f32x4){0.f,0.f,0.f,0.f};
  const short* nmp = reinterpret_cast<const short*>(nmT);
  for (int ks = 0; ks < 16; ++ks){
    short8 af[4];
    #pragma unroll
    for (int mt = 0; mt < 4; ++mt){
      int row = mt * 16 + li;
      af[mt] = *reinterpret_cast<const short8*>(
          smem + row * 1024 + ((ks * 64 + gr * 16) ^ ((row & 7) << 4)));
    }
    #pragma unroll
    for (int nt = 0; nt < 2; ++nt){
      short8 bv = *reinterpret_cast<const short8*>(
          nmp + (size_t)(w * 32 + nt * 16 + li) * Kk + ks * 32 + gr * 8);
      #pragma unroll
      for (int mt = 0; mt < 4; ++mt)
        acc2[mt][nt] = __builtin_amdgcn_mfma_f32_16x16x32_bf16(af[mt], bv, acc2[mt][nt], 0, 0, 0);
    }
  }
  __syncthreads();                               // rz visible to all waves
  int b = px0 >> 12, hw0 = px0 & 4095;
  #pragma unroll
  for (int mt = 0; mt < 4; ++mt){
    int pb = mt * 16 + gr * 4;
    float r0 = rz[pb + 0], r1 = rz[pb + 1], r2 = rz[pb + 2], r3 = rz[pb + 3];
    #pragma unroll
    for (int nt = 0; nt < 2; ++nt){
      int c = w * 32 + nt * 16 + li;
      f32x4 v;
      v[0] = acc2[mt][nt][0] * r0;
      v[1] = acc2[mt][nt][1] * r1;
      v[2] = acc2[mt][nt][2] * r2;
      v[3] = acc2[mt][nt][3] * r3;
      *reinterpret_cast<f32x4*>(out + ((size_t)b * Cc + c) * HW + hw0 + pb) = v;
    }
  }
}

extern "C" void kernel_launch(void* const* d_in, const int* in_sizes, int n_in,
                              void* d_out, int out_size, void* d_ws, size_t ws_size,
                              hipStream_t stream) {
  (void)in_sizes; (void)n_in; (void)out_size; (void)ws_size;
  const float* x = (const float*)d_in[0];   // (16,256,64,64)
  const float* m = (const float*)d_in[1];   // (512,256)
  float* out    = (float*)d_out;                       // 16777216 f32
  float* score2 = (float*)d_out + (size_t)Nn * Cc;     // 33554432 f32

  char* ws = (char*)d_ws;
  unsigned short* xn  = (unsigned short*)(ws);                 // 33554432 B
  float*          nrm = (float*)(ws + 33554432);               //   262144 B
  unsigned short* mn  = (unsigned short*)(ws + 33816576);      //   262144 B
  int*            ei  = (int*)(ws + 34078720);                 //   262144 B
  float*          es2 = (float*)(ws + 34340864);               //  1048576 B
  float*          ec2 = (float*)(ws + 35389440);               //     4096 B
  unsigned short* mn2 = (unsigned short*)(ws + 35393536);      //   262144 B
  unsigned short* nmT = (unsigned short*)(ws + 35655680);      //   262144 B

  k_prep        <<<1024, 256, 0, stream>>>(x, nrm, xn);
  k_mnorm       <<<512,  64,  0, stream>>>(m, mn);
  k_score_argmax<<<1024, 512, 0, stream>>>(xn, mn, ei);
  k_segsum      <<<1024, 256, 0, stream>>>(ei, xn, nrm, es2, ec2);
  k_update      <<<512,  64,  0, stream>>>(es2, ec2, m, mn2, nmT);
  k_out         <<<1024, 512, 0, stream>>>(xn, mn2, nmT, out, score2);
}

// Round 4
// 188.583 us; speedup vs baseline: 1.5299x; 1.0054x over previous
//
#include <hip/hip_runtime.h>

#define Bb 16
#define Cc 256
#define HW 4096
#define Nn 65536
#define Kk 512

typedef __attribute__((ext_vector_type(4))) float f32x4;
typedef __attribute__((ext_vector_type(8))) short short8;

__device__ __forceinline__ float bf2f(unsigned int u){
  union { float f; unsigned int i; } v; v.i = u << 16; return v.f;
}
__device__ __forceinline__ unsigned short f2bf(float f){
  unsigned int i = __float_as_uint(f);
  unsigned int r = (i + 0x7fffu + ((i >> 16) & 1u)) >> 16;
  return (unsigned short)r;
}

// ---------------- K1b: normalize codebook m -> mn bf16 ----------------
__global__ __launch_bounds__(64) void k_mnorm(const float* __restrict__ m,
                                              unsigned short* __restrict__ mn){
  int k = blockIdx.x, l = threadIdx.x;
  float4 v = *reinterpret_cast<const float4*>(m + (size_t)k * Cc + l * 4);
  float ss = v.x*v.x + v.y*v.y + v.z*v.z + v.w*v.w;
  #pragma unroll
  for (int off = 1; off < 64; off <<= 1) ss += __shfl_xor(ss, off, 64);
  float rn = 1.0f / fmaxf(sqrtf(ss), 1e-12f);
  ushort4 o;
  o.x = f2bf(v.x*rn); o.y = f2bf(v.y*rn); o.z = f2bf(v.z*rn); o.w = f2bf(v.w*rn);
  *reinterpret_cast<ushort4*>(mn + (size_t)k * Cc + l * 4) = o;
}

// ---------------- K_prep_score: fused load+norm+stash + GEMM1(raw)+argmax ----------------
// 1024 blocks = (b, 64-px strip), 512 thr / 8 waves.
// argmax_k (x.mn_k / ||x||) == argmax_k (x.mn_k)  -> GEMM on RAW bf16 x tile.
__global__ __launch_bounds__(512, 4) void k_prep_score(const float* __restrict__ x,
                                                       const unsigned short* __restrict__ mn,
                                                       float* __restrict__ rs,
                                                       unsigned short* __restrict__ xr,
                                                       int* __restrict__ eind){
  __shared__ __align__(16) char ldsB[32768];   // [64 px][512 B] raw bf16, XOR-swizzled
  __shared__ float red[8][64];
  __shared__ float smax[8][64];
  __shared__ int   sidx[8][64];
  int t = threadIdx.x, w = t >> 6, l = t & 63, gr = l >> 4, li = l & 15;
  int b = blockIdx.x >> 6;
  int hw0 = (blockIdx.x & 63) << 6;
  int qq = t & 7;            // 8-px window
  int cl = t >> 3;           // 0..63 channel-in-chunk
  float aq[8];
  #pragma unroll
  for (int j = 0; j < 8; ++j) aq[j] = 0.f;
  #pragma unroll
  for (int ch = 0; ch < 4; ++ch){
    const float* src = x + ((size_t)b * Cc + ch * 64 + cl) * HW + hw0 + qq * 8;
    float4 v0 = reinterpret_cast<const float4*>(src)[0];
    float4 v1 = reinterpret_cast<const float4*>(src)[1];
    float vv[8] = {v0.x,v0.y,v0.z,v0.w, v1.x,v1.y,v1.z,v1.w};
    int chb = ch * 128 + cl * 2;
    #pragma unroll
    for (int j = 0; j < 8; ++j){
      float v = vv[j];
      aq[j] += v * v;
      int px = qq * 8 + j;
      int sw = ((px ^ (px >> 4)) & 7) << 4;
      *reinterpret_cast<unsigned short*>(ldsB + px * 512 + (chb ^ sw)) = f2bf(v);
    }
  }
  // reduce sumsq over channel-lanes (lane bits 3..5) within wave
  #pragma unroll
  for (int j = 0; j < 8; ++j){
    float s = aq[j];
    s += __shfl_xor(s, 8, 64);
    s += __shfl_xor(s, 16, 64);
    s += __shfl_xor(s, 32, 64);
    aq[j] = s;
  }
  int j0 = l >> 3;
  red[w][qq * 8 + j0] = aq[j0];
  __syncthreads();                             // stash + red complete
  if (t < 64){
    float ss = 0.f;
    #pragma unroll
    for (int ww = 0; ww < 8; ++ww) ss += red[ww][t];
    rs[(size_t)b * HW + hw0 + t] = 1.0f / fmaxf(sqrtf(ss), 1e-12f);
  }
  // GEMM1 on raw tile: wave w owns k in [w*64, w*64+64)
  f32x4 acc[4][4];
  #pragma unroll
  for (int mt = 0; mt < 4; ++mt)
    #pragma unroll
    for (int nt = 0; nt < 4; ++nt)
      acc[mt][nt] = (f32x4){0.f,0.f,0.f,0.f};
  const short* mnp = reinterpret_cast<const short*>(mn);
  for (int ks = 0; ks < 8; ++ks){
    short8 af[4];
    #pragma unroll
    for (int mt = 0; mt < 4; ++mt){
      int row = mt * 16 + li;
      int sw = ((row ^ (row >> 4)) & 7) << 4;
      af[mt] = *reinterpret_cast<const short8*>(
          ldsB + row * 512 + ((ks * 64 + gr * 16) ^ sw));
    }
    #pragma unroll
    for (int nt = 0; nt < 4; ++nt){
      short8 bv = *reinterpret_cast<const short8*>(
          mnp + (size_t)(w * 64 + nt * 16 + li) * Cc + ks * 32 + gr * 8);
      #pragma unroll
      for (int mt = 0; mt < 4; ++mt)
        acc[mt][nt] = __builtin_amdgcn_mfma_f32_16x16x32_bf16(af[mt], bv, acc[mt][nt], 0, 0, 0);
    }
  }
  // per-wave argmax over its 64 k
  #pragma unroll
  for (int mt = 0; mt < 4; ++mt){
    #pragma unroll
    for (int r = 0; r < 4; ++r){
      float best = acc[mt][0][r]; int bi = w * 64 + li;
      #pragma unroll
      for (int nt = 1; nt < 4; ++nt){
        float v = acc[mt][nt][r]; int ii = w * 64 + nt * 16 + li;
        if (v > best){ best = v; bi = ii; }
      }
      #pragma unroll
      for (int off = 1; off < 16; off <<= 1){
        float ov = __shfl_xor(best, off, 64);
        int   oi = __shfl_xor(bi,   off, 64);
        if (ov > best || (ov == best && oi < bi)){ best = ov; bi = oi; }
      }
      if (li == 0){ int pr = mt * 16 + gr * 4 + r; smax[w][pr] = best; sidx[w][pr] = bi; }
    }
  }
  __syncthreads();
  if (t < 64){
    float best = smax[0][t]; int bi = sidx[0][t];
    #pragma unroll
    for (int ww = 1; ww < 8; ++ww){
      float v = smax[ww][t]; int ii = sidx[ww][t];
      if (v > best || (v == best && ii < bi)){ best = v; bi = ii; }
    }
    eind[(size_t)b * HW + hw0 + t] = bi;
  }
  // writeout raw xr (1KB-contiguous per wave)
  char* dst = reinterpret_cast<char*>(xr) + ((size_t)b * HW + hw0) * 512;
  #pragma unroll
  for (int i = 0; i < 4; ++i){
    int px = i * 16 + (t >> 5);
    int colb = (t & 31) * 16;
    int sw = ((px ^ (px >> 4)) & 7) << 4;
    int4 rv = *reinterpret_cast<const int4*>(ldsB + px * 512 + (colb ^ sw));
    *reinterpret_cast<int4*>(dst + (size_t)px * 512 + colb) = rv;
  }
}

// ---------------- K3: deterministic segment-sum (block = (k, half)) ----------------
__global__ __launch_bounds__(256) void k_segsum(const int* __restrict__ eind,
                                                const unsigned short* __restrict__ xr,
                                                float* __restrict__ es2,
                                                float* __restrict__ ec2){
  int kk = blockIdx.x >> 1, h = blockIdx.x & 1;
  int t = threadIdx.x, w = t >> 6, l = t & 63;
  float a0=0.f,a1=0.f,a2=0.f,a3=0.f;
  int cnt = 0;
  int base = h * 32768 + w * 8192;
  for (int it = 0; it < 32; ++it){
    int pxb = base + it * 256;
    int4 e = *reinterpret_cast<const int4*>(eind + pxb + l * 4);
    #pragma unroll
    for (int comp = 0; comp < 4; ++comp){
      int ev = comp == 0 ? e.x : comp == 1 ? e.y : comp == 2 ? e.z : e.w;
      unsigned long long mask = __ballot(ev == kk);
      cnt += (int)__popcll(mask);
      while (mask){
        int src = __ffsll((unsigned long long)mask) - 1;
        mask &= mask - 1;
        int px = pxb + src * 4 + comp;
        ushort4 uv = *reinterpret_cast<const ushort4*>(xr + (size_t)px * Cc + l * 4);
        a0 += bf2f(uv.x); a1 += bf2f(uv.y);
        a2 += bf2f(uv.z); a3 += bf2f(uv.w);
      }
    }
  }
  __shared__ float red[4][256];
  __shared__ float rcnt[4];
  red[w][l*4+0]=a0; red[w][l*4+1]=a1; red[w][l*4+2]=a2; red[w][l*4+3]=a3;
  if (l == 0) rcnt[w] = (float)cnt;
  __syncthreads();
  float s = red[0][t] + red[1][t] + red[2][t] + red[3][t];
  es2[(size_t)blockIdx.x * Cc + t] = s;
  if (t == 0) ec2[blockIdx.x] = rcnt[0] + rcnt[1] + rcnt[2] + rcnt[3];
}

// ---------------- K4: EMA update (sums both halves) -> mn2 + new_m^T ----------------
__global__ __launch_bounds__(64) void k_update(const float* __restrict__ es2,
                                               const float* __restrict__ ec2,
                                               const float* __restrict__ m,
                                               unsigned short* __restrict__ mn2,
                                               unsigned short* __restrict__ nmT){
  int k = blockIdx.x, l = threadIdx.x;
  float4 s0 = *reinterpret_cast<const float4*>(es2 + ((size_t)2*k  ) * Cc + l * 4);
  float4 s1 = *reinterpret_cast<const float4*>(es2 + ((size_t)2*k+1) * Cc + l * 4);
  float4 mv = *reinterpret_cast<const float4*>(m   + (size_t)k * Cc + l * 4);
  float inv = 1.0f / (ec2[2*k] + ec2[2*k+1] + 1e-6f);
  float nx = mv.x * 0.999f + (s0.x + s1.x) * inv * 0.001f;
  float ny = mv.y * 0.999f + (s0.y + s1.y) * inv * 0.001f;
  float nz = mv.z * 0.999f + (s0.z + s1.z) * inv * 0.001f;
  float nw = mv.w * 0.999f + (s0.w + s1.w) * inv * 0.001f;
  float ss = nx*nx + ny*ny + nz*nz + nw*nw;
  #pragma unroll
  for (int off = 1; off < 64; off <<= 1) ss += __shfl_xor(ss, off, 64);
  float rn = 1.0f / fmaxf(sqrtf(ss), 1e-12f);
  ushort4 o;
  o.x = f2bf(nx*rn); o.y = f2bf(ny*rn); o.z = f2bf(nz*rn); o.w = f2bf(nw*rn);
  *reinterpret_cast<ushort4*>(mn2 + (size_t)k * Cc + l * 4) = o;
  nmT[(size_t)(l*4+0) * Kk + k] = f2bf(nx);
  nmT[(size_t)(l*4+1) * Kk + k] = f2bf(ny);
  nmT[(size_t)(l*4+2) * Kk + k] = f2bf(nz);
  nmT[(size_t)(l*4+3) * Kk + k] = f2bf(nw);
}

// ---------------- K5: score2 (raw GEMM * rs) -> softmax -> out ----------------
__global__ __launch_bounds__(512, 4) void k_out(const unsigned short* __restrict__ xr,
                                                const float* __restrict__ rs,
                                                const unsigned short* __restrict__ mn2,
                                                const unsigned short* __restrict__ nmT,
                                                float* __restrict__ out,
                                                float* __restrict__ score2){
  __shared__ __align__(16) char smem[65536];   // xr tile (32K, overlaid) -> P tile (64K)
  __shared__ float wbuf[8 * 64];
  __shared__ float rz[64];
  __shared__ float rsl[64];
  int t = threadIdx.x, w = t >> 6, l = t & 63, gr = l >> 4, li = l & 15;
  int px0 = blockIdx.x * 64;
  const char* gsrc = reinterpret_cast<const char*>(xr + (size_t)px0 * Cc);
  #pragma unroll
  for (int j = 0; j < 4; ++j){
    int chunk = j * 512 + t;
    int rr = chunk >> 5, slot = chunk & 31;
    int4 v = *reinterpret_cast<const int4*>(gsrc + rr * 512 + slot * 16);
    *reinterpret_cast<int4*>(smem + rr * 512 + ((slot * 16) ^ ((rr & 7) << 4))) = v;
  }
  if (t < 64) rsl[t] = rs[px0 + t];
  __syncthreads();
  // GEMM1: raw xr @ mn2^T  (wave w owns k in [w*64, w*64+64))
  f32x4 acc[4][4];
  #pragma unroll
  for (int mt = 0; mt < 4; ++mt)
    #pragma unroll
    for (int nt = 0; nt < 4; ++nt)
      acc[mt][nt] = (f32x4){0.f,0.f,0.f,0.f};
  const short* mnp = reinterpret_cast<const short*>(mn2);
  for (int ks = 0; ks < 8; ++ks){
    short8 af[4];
    #pragma unroll
    for (int mt = 0; mt < 4; ++mt){
      int row = mt * 16 + li;
      af[mt] = *reinterpret_cast<const short8*>(
          smem + row * 512 + ((ks * 64 + gr * 16) ^ ((row & 7) << 4)));
    }
    #pragma unroll
    for (int nt = 0; nt < 4; ++nt){
      short8 bv = *reinterpret_cast<const short8*>(
          mnp + (size_t)(w * 64 + nt * 16 + li) * Cc + ks * 32 + gr * 8);
      #pragma unroll
      for (int mt = 0; mt < 4; ++mt)
        acc[mt][nt] = __builtin_amdgcn_mfma_f32_16x16x32_bf16(af[mt], bv, acc[mt][nt], 0, 0, 0);
    }
  }
  float* s2 = score2 + (size_t)px0 * Kk;
  __syncthreads();                               // all GEMM1 LDS reads done before P overlay
  // scale by rs (f32), store score2, exp (|s|<=1.01), P bf16 to LDS, partial sums
  #pragma unroll
  for (int mt = 0; mt < 4; ++mt){
    #pragma unroll
    for (int r = 0; r < 4; ++r){
      int pr = mt * 16 + gr * 4 + r;
      float rsv = rsl[pr];
      float s = 0.f;
      #pragma unroll
      for (int nt = 0; nt < 4; ++nt){
        float v = acc[mt][nt][r] * rsv;
        s2[(size_t)pr * Kk + w * 64 + nt * 16 + li] = v;
        float p = __expf(v);
        s += p;
        int colb = (w * 64 + nt * 16 + li) * 2;
        *reinterpret_cast<unsigned short*>(smem + pr * 1024 + (colb ^ ((pr & 7) << 4))) = f2bf(p);
      }
      #pragma unroll
      for (int off = 1; off < 16; off <<= 1) s += __shfl_xor(s, off, 64);
      if (li == 0) wbuf[w * 64 + pr] = s;
    }
  }
  __syncthreads();                               // P + wbuf(sums) ready
  if (t < 64){
    float s = wbuf[t];
    #pragma unroll
    for (int ww = 1; ww < 8; ++ww) s += wbuf[ww * 64 + t];
    rz[t] = 1.0f / s;
  }
  // GEMM2: out tile = P @ new_m  (wave w owns c in [w*32, w*32+32))
  f32x4 acc2[4][2];
  #pragma unroll
  for (int mt = 0; mt < 4; ++mt)
    #pragma unroll
    for (int nt = 0; nt < 2; ++nt)
      acc2[mt][nt] = (f32x4){0.f,0.f,0.f,0.f};
  const short* nmp = reinterpret_cast<const short*>(nmT);
  for (int ks = 0; ks < 16; ++ks){
    short8 af[4];
    #pragma unroll
    for (int mt = 0; mt < 4; ++mt){
      int row = mt * 16 + li;
      af[mt] = *reinterpret_cast<const short8*>(
          smem + row * 1024 + ((ks * 64 + gr * 16) ^ ((row & 7) << 4)));
    }
    #pragma unroll
    for (int nt = 0; nt < 2; ++nt){
      short8 bv = *reinterpret_cast<const short8*>(
          nmp + (size_t)(w * 32 + nt * 16 + li) * Kk + ks * 32 + gr * 8);
      #pragma unroll
      for (int mt = 0; mt < 4; ++mt)
        acc2[mt][nt] = __builtin_amdgcn_mfma_f32_16x16x32_bf16(af[mt], bv, acc2[mt][nt], 0, 0, 0);
    }
  }
  __syncthreads();                               // rz visible to all waves
  int b = px0 >> 12, hw0 = px0 & 4095;
  #pragma unroll
  for (int mt = 0; mt < 4; ++mt){
    int pb = mt * 16 + gr * 4;
    float r0 = rz[pb + 0], r1 = rz[pb + 1], r2 = rz[pb + 2], r3 = rz[pb + 3];
    #pragma unroll
    for (int nt = 0; nt < 2; ++nt){
      int c = w * 32 + nt * 16 + li;
      f32x4 v;
      v[0] = acc2[mt][nt][0] * r0;
      v[1] = acc2[mt][nt][1] * r1;
      v[2] = acc2[mt][nt][2] * r2;
      v[3] = acc2[mt][nt][3] * r3;
      *reinterpret_cast<f32x4*>(out + ((size_t)b * Cc + c) * HW + hw0 + pb) = v;
    }
  }
}

extern "C" void kernel_launch(void* const* d_in, const int* in_sizes, int n_in,
                              void* d_out, int out_size, void* d_ws, size_t ws_size,
                              hipStream_t stream) {
  (void)in_sizes; (void)n_in; (void)out_size; (void)ws_size;
  const float* x = (const float*)d_in[0];   // (16,256,64,64)
  const float* m = (const float*)d_in[1];   // (512,256)
  float* out    = (float*)d_out;                       // 16777216 f32
  float* score2 = (float*)d_out + (size_t)Nn * Cc;     // 33554432 f32

  char* ws = (char*)d_ws;
  unsigned short* xr  = (unsigned short*)(ws);                 // 33554432 B raw bf16 x, px-major
  float*          rsb = (float*)(ws + 33554432);               //   262144 B  1/||x||
  unsigned short* mn  = (unsigned short*)(ws + 33816576);      //   262144 B
  int*            ei  = (int*)(ws + 34078720);                 //   262144 B
  float*          es2 = (float*)(ws + 34340864);               //  1048576 B
  float*          ec2 = (float*)(ws + 35389440);               //     4096 B
  unsigned short* mn2 = (unsigned short*)(ws + 35393536);      //   262144 B
  unsigned short* nmT = (unsigned short*)(ws + 35655680);      //   262144 B

  k_mnorm       <<<512,  64,  0, stream>>>(m, mn);
  k_prep_score  <<<1024, 512, 0, stream>>>(x, mn, rsb, xr, ei);
  k_segsum      <<<1024, 256, 0, stream>>>(ei, xr, es2, ec2);
  k_update      <<<512,  64,  0, stream>>>(es2, ec2, m, mn2, nmT);
  k_out         <<<1024, 512, 0, stream>>>(xr, rsb, mn2, nmT, out, score2);
}

// Round 5
// 182.619 us; speedup vs baseline: 1.5799x; 1.0327x over previous
//
#include <hip/hip_runtime.h>

#define Bb 16
#define Cc 256
#define HW 4096
#define Nn 65536
#define Kk 512

typedef __attribute__((ext_vector_type(4))) float f32x4;
typedef __attribute__((ext_vector_type(8))) short short8;

__device__ __forceinline__ float bf2f(unsigned int u){
  union { float f; unsigned int i; } v; v.i = u << 16; return v.f;
}
__device__ __forceinline__ unsigned short f2bf(float f){
  unsigned int i = __float_as_uint(f);
  unsigned int r = (i + 0x7fffu + ((i >> 16) & 1u)) >> 16;
  return (unsigned short)r;
}

// ---------------- K1b: normalize codebook m -> mn bf16 ----------------
__global__ __launch_bounds__(64) void k_mnorm(const float* __restrict__ m,
                                              unsigned short* __restrict__ mn){
  int k = blockIdx.x, l = threadIdx.x;
  float4 v = *reinterpret_cast<const float4*>(m + (size_t)k * Cc + l * 4);
  float ss = v.x*v.x + v.y*v.y + v.z*v.z + v.w*v.w;
  #pragma unroll
  for (int off = 1; off < 64; off <<= 1) ss += __shfl_xor(ss, off, 64);
  float rn = 1.0f / fmaxf(sqrtf(ss), 1e-12f);
  ushort4 o;
  o.x = f2bf(v.x*rn); o.y = f2bf(v.y*rn); o.z = f2bf(v.z*rn); o.w = f2bf(v.w*rn);
  *reinterpret_cast<ushort4*>(mn + (size_t)k * Cc + l * 4) = o;
}

// ---------------- K_prep_score: fused load+norm+stash + GEMM1(raw)+argmax ----------------
// 1024 blocks = (b, 64-px strip), 512 thr / 8 waves.
// Thread: px = wave-lane l, channels w*32..w*32+32 (coalesced 256B wave loads).
__global__ __launch_bounds__(512, 4) void k_prep_score(const float* __restrict__ x,
                                                       const unsigned short* __restrict__ mn,
                                                       float* __restrict__ rs,
                                                       unsigned short* __restrict__ xr,
                                                       int* __restrict__ eind){
  __shared__ __align__(16) char ldsB[32768];   // [64 px][512 B] raw bf16, XOR-swizzled
  __shared__ float red[8][64];
  __shared__ float smax[8][64];
  __shared__ int   sidx[8][64];
  int t = threadIdx.x, w = t >> 6, l = t & 63, gr = l >> 4, li = l & 15;
  int b = blockIdx.x >> 6;
  int hw0 = (blockIdx.x & 63) << 6;
  const float* src = x + ((size_t)b * Cc + w * 32) * HW + hw0 + l;
  float ss = 0.f;
  unsigned int pk[16];
  #pragma unroll
  for (int j = 0; j < 16; ++j){
    float v0 = src[(size_t)(2*j    ) * HW];
    float v1 = src[(size_t)(2*j + 1) * HW];
    ss += v0 * v0 + v1 * v1;
    pk[j] = (unsigned int)f2bf(v0) | ((unsigned int)f2bf(v1) << 16);
  }
  #pragma unroll
  for (int q = 0; q < 4; ++q){
    int colb = w * 64 + q * 16;
    int4 vv;
    vv.x = (int)pk[q*4+0]; vv.y = (int)pk[q*4+1];
    vv.z = (int)pk[q*4+2]; vv.w = (int)pk[q*4+3];
    *reinterpret_cast<int4*>(ldsB + l * 512 + (colb ^ ((l & 7) << 4))) = vv;
  }
  red[w][l] = ss;
  __syncthreads();                             // stash + red complete
  if (t < 64){
    float s = 0.f;
    #pragma unroll
    for (int ww = 0; ww < 8; ++ww) s += red[ww][t];
    rs[(size_t)b * HW + hw0 + t] = 1.0f / fmaxf(sqrtf(s), 1e-12f);
  }
  // GEMM1 on raw tile: wave w owns k in [w*64, w*64+64)
  f32x4 acc[4][4];
  #pragma unroll
  for (int mt = 0; mt < 4; ++mt)
    #pragma unroll
    for (int nt = 0; nt < 4; ++nt)
      acc[mt][nt] = (f32x4){0.f,0.f,0.f,0.f};
  const short* mnp = reinterpret_cast<const short*>(mn);
  for (int ks = 0; ks < 8; ++ks){
    short8 af[4];
    #pragma unroll
    for (int mt = 0; mt < 4; ++mt){
      int row = mt * 16 + li;
      af[mt] = *reinterpret_cast<const short8*>(
          ldsB + row * 512 + ((ks * 64 + gr * 16) ^ ((row & 7) << 4)));
    }
    #pragma unroll
    for (int nt = 0; nt < 4; ++nt){
      short8 bv = *reinterpret_cast<const short8*>(
          mnp + (size_t)(w * 64 + nt * 16 + li) * Cc + ks * 32 + gr * 8);
      #pragma unroll
      for (int mt = 0; mt < 4; ++mt)
        acc[mt][nt] = __builtin_amdgcn_mfma_f32_16x16x32_bf16(af[mt], bv, acc[mt][nt], 0, 0, 0);
    }
  }
  // per-wave argmax over its 64 k
  #pragma unroll
  for (int mt = 0; mt < 4; ++mt){
    #pragma unroll
    for (int r = 0; r < 4; ++r){
      float best = acc[mt][0][r]; int bi = w * 64 + li;
      #pragma unroll
      for (int nt = 1; nt < 4; ++nt){
        float v = acc[mt][nt][r]; int ii = w * 64 + nt * 16 + li;
        if (v > best){ best = v; bi = ii; }
      }
      #pragma unroll
      for (int off = 1; off < 16; off <<= 1){
        float ov = __shfl_xor(best, off, 64);
        int   oi = __shfl_xor(bi,   off, 64);
        if (ov > best || (ov == best && oi < bi)){ best = ov; bi = oi; }
      }
      if (li == 0){ int pr = mt * 16 + gr * 4 + r; smax[w][pr] = best; sidx[w][pr] = bi; }
    }
  }
  __syncthreads();
  if (t < 64){
    float best = smax[0][t]; int bi = sidx[0][t];
    #pragma unroll
    for (int ww = 1; ww < 8; ++ww){
      float v = smax[ww][t]; int ii = sidx[ww][t];
      if (v > best || (v == best && ii < bi)){ best = v; bi = ii; }
    }
    eind[(size_t)b * HW + hw0 + t] = bi;
  }
  // writeout raw xr (1KB-contiguous per wave)
  char* dst = reinterpret_cast<char*>(xr) + ((size_t)b * HW + hw0) * 512;
  #pragma unroll
  for (int i = 0; i < 4; ++i){
    int px = i * 16 + (t >> 5);
    int colb = (t & 31) * 16;
    int4 rv = *reinterpret_cast<const int4*>(ldsB + px * 512 + (colb ^ ((px & 7) << 4)));
    *reinterpret_cast<int4*>(dst + (size_t)px * 512 + colb) = rv;
  }
}

// ---------------- K3: deterministic segment-sum (block = (k, quarter)) ----------------
__global__ __launch_bounds__(256) void k_segsum(const int* __restrict__ eind,
                                                const unsigned short* __restrict__ xr,
                                                float* __restrict__ es4,
                                                float* __restrict__ ec4){
  int kk = blockIdx.x >> 2, qr = blockIdx.x & 3;
  int t = threadIdx.x, w = t >> 6, l = t & 63;
  float a0=0.f,a1=0.f,a2=0.f,a3=0.f;
  int cnt = 0;
  int base = qr * 16384 + w * 4096;
  for (int it = 0; it < 16; ++it){
    int pxb = base + it * 256;
    int4 e = *reinterpret_cast<const int4*>(eind + pxb + l * 4);
    #pragma unroll
    for (int comp = 0; comp < 4; ++comp){
      int ev = comp == 0 ? e.x : comp == 1 ? e.y : comp == 2 ? e.z : e.w;
      unsigned long long mask = __ballot(ev == kk);
      cnt += (int)__popcll(mask);
      while (mask){
        int src = __ffsll((unsigned long long)mask) - 1;
        mask &= mask - 1;
        int px = pxb + src * 4 + comp;
        ushort4 uv = *reinterpret_cast<const ushort4*>(xr + (size_t)px * Cc + l * 4);
        a0 += bf2f(uv.x); a1 += bf2f(uv.y);
        a2 += bf2f(uv.z); a3 += bf2f(uv.w);
      }
    }
  }
  __shared__ float red[4][256];
  __shared__ float rcnt[4];
  red[w][l*4+0]=a0; red[w][l*4+1]=a1; red[w][l*4+2]=a2; red[w][l*4+3]=a3;
  if (l == 0) rcnt[w] = (float)cnt;
  __syncthreads();
  float s = red[0][t] + red[1][t] + red[2][t] + red[3][t];
  es4[(size_t)blockIdx.x * Cc + t] = s;
  if (t == 0) ec4[blockIdx.x] = rcnt[0] + rcnt[1] + rcnt[2] + rcnt[3];
}

// ---------------- K4: EMA update (sums 4 quarters) -> mn2 + new_m^T ----------------
__global__ __launch_bounds__(64) void k_update(const float* __restrict__ es4,
                                               const float* __restrict__ ec4,
                                               const float* __restrict__ m,
                                               unsigned short* __restrict__ mn2,
                                               unsigned short* __restrict__ nmT){
  int k = blockIdx.x, l = threadIdx.x;
  float sx = 0.f, sy = 0.f, sz = 0.f, sw = 0.f, cs = 0.f;
  #pragma unroll
  for (int q = 0; q < 4; ++q){
    float4 s = *reinterpret_cast<const float4*>(es4 + ((size_t)(4*k+q)) * Cc + l * 4);
    sx += s.x; sy += s.y; sz += s.z; sw += s.w;
    cs += ec4[4*k+q];
  }
  float4 mv = *reinterpret_cast<const float4*>(m + (size_t)k * Cc + l * 4);
  float inv = 1.0f / (cs + 1e-6f);
  float nx = mv.x * 0.999f + sx * inv * 0.001f;
  float ny = mv.y * 0.999f + sy * inv * 0.001f;
  float nz = mv.z * 0.999f + sz * inv * 0.001f;
  float nw = mv.w * 0.999f + sw * inv * 0.001f;
  float ss = nx*nx + ny*ny + nz*nz + nw*nw;
  #pragma unroll
  for (int off = 1; off < 64; off <<= 1) ss += __shfl_xor(ss, off, 64);
  float rn = 1.0f / fmaxf(sqrtf(ss), 1e-12f);
  ushort4 o;
  o.x = f2bf(nx*rn); o.y = f2bf(ny*rn); o.z = f2bf(nz*rn); o.w = f2bf(nw*rn);
  *reinterpret_cast<ushort4*>(mn2 + (size_t)k * Cc + l * 4) = o;
  nmT[(size_t)(l*4+0) * Kk + k] = f2bf(nx);
  nmT[(size_t)(l*4+1) * Kk + k] = f2bf(ny);
  nmT[(size_t)(l*4+2) * Kk + k] = f2bf(nz);
  nmT[(size_t)(l*4+3) * Kk + k] = f2bf(nw);
}

// ---------------- K5: swapped GEMM1 (D[k][px]) -> float4 score2 -> softmax -> out ----------------
__global__ __launch_bounds__(512, 4) void k_out(const unsigned short* __restrict__ xr,
                                                const float* __restrict__ rs,
                                                const unsigned short* __restrict__ mn2,
                                                const unsigned short* __restrict__ nmT,
                                                float* __restrict__ out,
                                                float* __restrict__ score2){
  __shared__ __align__(16) char smem[65536];   // xr tile (32K, overlaid) -> P tile (64K)
  __shared__ float wbuf[8 * 64];
  __shared__ float rz[64];
  __shared__ float rsl[64];
  int t = threadIdx.x, w = t >> 6, l = t & 63, gr = l >> 4, li = l & 15;
  int px0 = blockIdx.x * 64;
  const char* gsrc = reinterpret_cast<const char*>(xr + (size_t)px0 * Cc);
  #pragma unroll
  for (int j = 0; j < 4; ++j){
    int chunk = j * 512 + t;
    int rr = chunk >> 5, slot = chunk & 31;
    int4 v = *reinterpret_cast<const int4*>(gsrc + rr * 512 + slot * 16);
    *reinterpret_cast<int4*>(smem + rr * 512 + ((slot * 16) ^ ((rr & 7) << 4))) = v;
  }
  if (t < 64) rsl[t] = rs[px0 + t];
  __syncthreads();
  // GEMM1': A = mn2 k-rows, B = xr px-rows -> D[row=k][col=px]; wave w owns k in [w*64,+64)
  f32x4 acc[4][4];                             // [kt][pt]
  #pragma unroll
  for (int kt = 0; kt < 4; ++kt)
    #pragma unroll
    for (int pt = 0; pt < 4; ++pt)
      acc[kt][pt] = (f32x4){0.f,0.f,0.f,0.f};
  const short* mnp = reinterpret_cast<const short*>(mn2);
  int kw = w * 64;
  for (int ks = 0; ks < 8; ++ks){
    short8 am[4];
    #pragma unroll
    for (int kt = 0; kt < 4; ++kt)
      am[kt] = *reinterpret_cast<const short8*>(
          mnp + (size_t)(kw + kt * 16 + li) * Cc + ks * 32 + gr * 8);
    short8 bx[4];
    #pragma unroll
    for (int pt = 0; pt < 4; ++pt){
      int row = pt * 16 + li;
      bx[pt] = *reinterpret_cast<const short8*>(
          smem + row * 512 + ((ks * 64 + gr * 16) ^ ((row & 7) << 4)));
    }
    #pragma unroll
    for (int kt = 0; kt < 4; ++kt)
      #pragma unroll
      for (int pt = 0; pt < 4; ++pt)
        acc[kt][pt] = __builtin_amdgcn_mfma_f32_16x16x32_bf16(am[kt], bx[pt], acc[kt][pt], 0, 0, 0);
  }
  __syncthreads();                             // all xr LDS reads done before P overlay
  // lane holds 4 consecutive k for px = pt*16+li: float4 score2 stores, b64 P writes
  float s[4] = {0.f, 0.f, 0.f, 0.f};
  float* s2 = score2 + (size_t)px0 * Kk;
  #pragma unroll
  for (int kt = 0; kt < 4; ++kt){
    #pragma unroll
    for (int pt = 0; pt < 4; ++pt){
      int px = pt * 16 + li;
      float rsv = rsl[px];
      f32x4 v = acc[kt][pt];
      v[0] *= rsv; v[1] *= rsv; v[2] *= rsv; v[3] *= rsv;
      *reinterpret_cast<f32x4*>(s2 + (size_t)px * Kk + kw + kt * 16 + gr * 4) = v;
      float p0 = __expf(v[0]), p1 = __expf(v[1]), p2 = __expf(v[2]), p3 = __expf(v[3]);
      s[pt] += (p0 + p1) + (p2 + p3);
      unsigned int lo = (unsigned int)f2bf(p0) | ((unsigned int)f2bf(p1) << 16);
      unsigned int hi = (unsigned int)f2bf(p2) | ((unsigned int)f2bf(p3) << 16);
      int colb = (kw + kt * 16 + gr * 4) * 2;
      uint2 pv; pv.x = lo; pv.y = hi;
      *reinterpret_cast<uint2*>(smem + px * 1024 + (colb ^ ((px & 7) << 4))) = pv;
    }
  }
  #pragma unroll
  for (int pt = 0; pt < 4; ++pt){
    s[pt] += __shfl_xor(s[pt], 16, 64);
    s[pt] += __shfl_xor(s[pt], 32, 64);
  }
  if (gr == 0){
    #pragma unroll
    for (int pt = 0; pt < 4; ++pt) wbuf[w * 64 + pt * 16 + li] = s[pt];
  }
  __syncthreads();                             // P + wbuf(sums) ready
  if (t < 64){
    float sum = wbuf[t];
    #pragma unroll
    for (int ww = 1; ww < 8; ++ww) sum += wbuf[ww * 64 + t];
    rz[t] = 1.0f / sum;
  }
  // GEMM2: out tile = P @ new_m  (A = P px-rows, B = nmT c-rows; wave w owns c in [w*32,+32))
  f32x4 acc2[4][2];
  #pragma unroll
  for (int mt = 0; mt < 4; ++mt)
    #pragma unroll
    for (int nt = 0; nt < 2; ++nt)
      acc2[mt][nt] = (f32x4){0.f,0.f,0.f,0.f};
  const short* nmp = reinterpret_cast<const short*>(nmT);
  for (int ks = 0; ks < 16; ++ks){
    short8 af[4];
    #pragma unroll
    for (int mt = 0; mt < 4; ++mt){
      int row = mt * 16 + li;
      af[mt] = *reinterpret_cast<const short8*>(
          smem + row * 1024 + ((ks * 64 + gr * 16) ^ ((row & 7) << 4)));
    }
    #pragma unroll
    for (int nt = 0; nt < 2; ++nt){
      short8 bv = *reinterpret_cast<const short8*>(
          nmp + (size_t)(w * 32 + nt * 16 + li) * Kk + ks * 32 + gr * 8);
      #pragma unroll
      for (int mt = 0; mt < 4; ++mt)
        acc2[mt][nt] = __builtin_amdgcn_mfma_f32_16x16x32_bf16(af[mt], bv, acc2[mt][nt], 0, 0, 0);
    }
  }
  __syncthreads();                             // rz visible to all waves
  int b = px0 >> 12, hw0 = px0 & 4095;
  #pragma unroll
  for (int mt = 0; mt < 4; ++mt){
    int pb = mt * 16 + gr * 4;
    float r0 = rz[pb + 0], r1 = rz[pb + 1], r2 = rz[pb + 2], r3 = rz[pb + 3];
    #pragma unroll
    for (int nt = 0; nt < 2; ++nt){
      int c = w * 32 + nt * 16 + li;
      f32x4 v;
      v[0] = acc2[mt][nt][0] * r0;
      v[1] = acc2[mt][nt][1] * r1;
      v[2] = acc2[mt][nt][2] * r2;
      v[3] = acc2[mt][nt][3] * r3;
      *reinterpret_cast<f32x4*>(out + ((size_t)b * Cc + c) * HW + hw0 + pb) = v;
    }
  }
}

extern "C" void kernel_launch(void* const* d_in, const int* in_sizes, int n_in,
                              void* d_out, int out_size, void* d_ws, size_t ws_size,
                              hipStream_t stream) {
  (void)in_sizes; (void)n_in; (void)out_size; (void)ws_size;
  const float* x = (const float*)d_in[0];   // (16,256,64,64)
  const float* m = (const float*)d_in[1];   // (512,256)
  float* out    = (float*)d_out;                       // 16777216 f32
  float* score2 = (float*)d_out + (size_t)Nn * Cc;     // 33554432 f32

  char* ws = (char*)d_ws;
  unsigned short* xr  = (unsigned short*)(ws);                 // 33554432 B raw bf16 x, px-major
  float*          rsb = (float*)(ws + 33554432);               //   262144 B  1/||x||
  unsigned short* mn  = (unsigned short*)(ws + 33816576);      //   262144 B
  int*            ei  = (int*)(ws + 34078720);                 //   262144 B
  float*          es4 = (float*)(ws + 34340864);               //  2097152 B
  float*          ec4 = (float*)(ws + 36438016);               //     8192 B
  unsigned short* mn2 = (unsigned short*)(ws + 36446208);      //   262144 B
  unsigned short* nmT = (unsigned short*)(ws + 36708352);      //   262144 B

  k_mnorm       <<<512,  64,  0, stream>>>(m, mn);
  k_prep_score  <<<1024, 512, 0, stream>>>(x, mn, rsb, xr, ei);
  k_segsum      <<<2048, 256, 0, stream>>>(ei, xr, es4, ec4);
  k_update      <<<512,  64,  0, stream>>>(es4, ec4, m, mn2, nmT);
  k_out         <<<1024, 512, 0, stream>>>(xr, rsb, mn2, nmT, out, score2);
}